// Round 2
// baseline (12200.932 us; speedup 1.0000x reference)
//
#include <hip/hip_runtime.h>
#include <stdint.h>

// Problem constants
// B=2, T=32, N=256, E=1024, H=16, D=64, L=2, K=256, MAXLEN=512
// tokens = B*T*N = 16384, processed in 4 chunks of 4096 rows.

__device__ __forceinline__ int tmap_dev(int m) {
    // temporal token m = (b*N+n)*T + t  ->  flat row (b*T+t)*N + n
    int bx = m >> 5;        // m / T (T=32)
    int s  = m & 31;        // t
    int b  = bx >> 8;       // bx / N (N=256)
    int n  = bx & 255;
    return (((b << 5) + s) << 8) + n;   // (b*32+s)*256 + n
}

// ---------------------------------------------------------------------------
// Generic row-major fp32 GEMM: C[m, n] = sum_k A[rin(m)][k] * B[k*ldb+n] + bias[n]
// tile 128x128, BK=16, 256 threads, 8x8 per thread.
// rin(m)  = map_in  ? tmap(m_off_in  + m) : (m_off_in  + m)
// rout(m) = map_out ? tmap(m_off_out + m) : (m_off_out + m)
// grid: (Nc/128, Mtile/128)
// ---------------------------------------------------------------------------
__global__ __launch_bounds__(256)
void gemm_rm(const float* __restrict__ A, const float* __restrict__ Bw,
             const float* __restrict__ bias, float* __restrict__ C,
             int ldb, int ldc, int Kd, int map_in, int map_out,
             int m_off_in, int m_off_out)
{
    __shared__ float As[16][132];
    __shared__ float Bs[16][128];
    const int tid = threadIdx.x;
    const int n0 = blockIdx.x * 128;
    const int m0 = blockIdx.y * 128;
    const int tx = tid & 15, ty = tid >> 4;

    float acc[8][8];
    #pragma unroll
    for (int i = 0; i < 8; i++)
        #pragma unroll
        for (int j = 0; j < 8; j++) acc[i][j] = 0.0f;

    // A staging assignment (fixed per thread across k0 iterations)
    const int r0  = tid >> 2;            // 0..63
    const int r1  = r0 + 64;
    const int kc0 = (tid & 3) << 2;      // 0,4,8,12
    const int gin0 = m_off_in + m0 + r0;
    const int gin1 = m_off_in + m0 + r1;
    const int gr0 = map_in ? tmap_dev(gin0) : gin0;
    const int gr1 = map_in ? tmap_dev(gin1) : gin1;
    const float* arow0 = A + (size_t)gr0 * Kd;
    const float* arow1 = A + (size_t)gr1 * Kd;

    // B staging assignment
    const int br0 = tid >> 5;            // 0..7
    const int bc0 = (tid & 31) << 2;     // 0..124

    for (int k0 = 0; k0 < Kd; k0 += 16) {
        float4 a0 = *(const float4*)(arow0 + k0 + kc0);
        float4 a1 = *(const float4*)(arow1 + k0 + kc0);
        float4 b0 = *(const float4*)(Bw + (size_t)(k0 + br0) * ldb + n0 + bc0);
        float4 b1 = *(const float4*)(Bw + (size_t)(k0 + br0 + 8) * ldb + n0 + bc0);

        As[kc0 + 0][r0] = a0.x; As[kc0 + 1][r0] = a0.y;
        As[kc0 + 2][r0] = a0.z; As[kc0 + 3][r0] = a0.w;
        As[kc0 + 0][r1] = a1.x; As[kc0 + 1][r1] = a1.y;
        As[kc0 + 2][r1] = a1.z; As[kc0 + 3][r1] = a1.w;
        *(float4*)&Bs[br0][bc0]     = b0;
        *(float4*)&Bs[br0 + 8][bc0] = b1;
        __syncthreads();

        #pragma unroll
        for (int kk = 0; kk < 16; kk++) {
            float a[8], b[8];
            #pragma unroll
            for (int i = 0; i < 8; i++) a[i] = As[kk][ty * 8 + i];
            #pragma unroll
            for (int j = 0; j < 8; j++) b[j] = Bs[kk][tx * 8 + j];
            #pragma unroll
            for (int i = 0; i < 8; i++)
                #pragma unroll
                for (int j = 0; j < 8; j++)
                    acc[i][j] = fmaf(a[i], b[j], acc[i][j]);
        }
        __syncthreads();
    }

    // epilogue: bias + store
    #pragma unroll
    for (int i = 0; i < 8; i++) {
        int gm = m_off_out + m0 + ty * 8 + i;
        int row = map_out ? tmap_dev(gm) : gm;
        float* cp = C + (size_t)row * ldc + n0 + tx * 8;
        const float* bp = bias + n0 + tx * 8;
        float4 v0, v1;
        v0.x = acc[i][0] + bp[0]; v0.y = acc[i][1] + bp[1];
        v0.z = acc[i][2] + bp[2]; v0.w = acc[i][3] + bp[3];
        v1.x = acc[i][4] + bp[4]; v1.y = acc[i][5] + bp[5];
        v1.z = acc[i][6] + bp[6]; v1.w = acc[i][7] + bp[7];
        *(float4*)cp       = v0;
        *(float4*)(cp + 4) = v1;
    }
}

// ---------------------------------------------------------------------------
// Relative-position attention on chunk-local Q/K/V (ld = 1024).
// Block: 256 threads = HPB heads x S rows. K staged in LDS (64 KB).
// Cb may alias Qb: each thread reads its q slice into registers before the
// barrier and writes the same (row, col-slice) at the end; blocks touch
// disjoint regions.
// grid: (chunk_rows/S, H/HPB)
// ---------------------------------------------------------------------------
template<int S, int HPB>
__global__ __launch_bounds__(256)
void attn_kernel(const float* __restrict__ Qb, const float* __restrict__ Kb,
                 const float* __restrict__ Vb, const float* __restrict__ RB,
                 float* __restrict__ Cb)
{
    __shared__ float Ks[16384];   // [HPB][S][64]
    const int tid = threadIdx.x;
    const int bx  = blockIdx.x;
    const int hg  = blockIdx.y;
    const int hh  = tid / S;
    const int s   = tid % S;
    const int head = hg * HPB + hh;
    const size_t rowbase = (size_t)bx * S;

    // load q into registers (before barrier; Cb may alias Qb)
    float q[64];
    {
        const float* qp = Qb + (rowbase + s) * 1024 + (size_t)head * 64;
        #pragma unroll
        for (int l = 0; l < 16; l++) {
            float4 t4 = *(const float4*)(qp + (l << 2));
            q[l * 4 + 0] = t4.x; q[l * 4 + 1] = t4.y;
            q[l * 4 + 2] = t4.z; q[l * 4 + 3] = t4.w;
        }
    }

    // stage K tile: HPB*S*64 = 16384 floats
    #pragma unroll
    for (int l = 0; l < 16; l++) {
        int i4 = tid + l * 256;
        int e  = i4 << 2;
        int hl  = e / (S * 64);
        int rem = e - hl * (S * 64);
        int j = rem >> 6, d = rem & 63;
        const float* kp = Kb + (rowbase + j) * 1024
                          + (size_t)(hg * HPB + hl) * 64 + d;
        *(float4*)&Ks[e] = *(const float4*)kp;
    }
    __syncthreads();

    const float* Kh  = Ks + hh * (S * 64);
    const float* rbp = RB + head;
    const int ds = 511 - s;   // rb row = j + 511 - s

    // pass 1: exact row max
    float mx = -3.0e38f;
    for (int j = 0; j < S; j++) {
        const float* kr = Kh + (j << 6);
        float d0 = 0.f, d1 = 0.f, d2 = 0.f, d3 = 0.f;
        #pragma unroll
        for (int d = 0; d < 64; d += 4) {
            d0 = fmaf(q[d + 0], kr[d + 0], d0);
            d1 = fmaf(q[d + 1], kr[d + 1], d1);
            d2 = fmaf(q[d + 2], kr[d + 2], d2);
            d3 = fmaf(q[d + 3], kr[d + 3], d3);
        }
        float sc = ((d0 + d1) + (d2 + d3)) * 0.125f + rbp[(size_t)(j + ds) * 16];
        mx = fmaxf(mx, sc);
    }

    // pass 2: weights + weighted V accumulation
    float ctx[64];
    #pragma unroll
    for (int d = 0; d < 64; d++) ctx[d] = 0.0f;
    float lsum = 0.0f;
    const float* vbase = Vb + rowbase * 1024 + (size_t)head * 64;
    for (int j = 0; j < S; j++) {
        const float* kr = Kh + (j << 6);
        float d0 = 0.f, d1 = 0.f, d2 = 0.f, d3 = 0.f;
        #pragma unroll
        for (int d = 0; d < 64; d += 4) {
            d0 = fmaf(q[d + 0], kr[d + 0], d0);
            d1 = fmaf(q[d + 1], kr[d + 1], d1);
            d2 = fmaf(q[d + 2], kr[d + 2], d2);
            d3 = fmaf(q[d + 3], kr[d + 3], d3);
        }
        float sc = ((d0 + d1) + (d2 + d3)) * 0.125f + rbp[(size_t)(j + ds) * 16];
        float p = __expf(sc - mx);
        lsum += p;
        const float* vr = vbase + (size_t)j * 1024;
        #pragma unroll
        for (int d = 0; d < 64; d += 4) {
            float4 v4 = *(const float4*)(vr + d);
            ctx[d + 0] = fmaf(p, v4.x, ctx[d + 0]);
            ctx[d + 1] = fmaf(p, v4.y, ctx[d + 1]);
            ctx[d + 2] = fmaf(p, v4.z, ctx[d + 2]);
            ctx[d + 3] = fmaf(p, v4.w, ctx[d + 3]);
        }
    }

    float inv = 1.0f / lsum;
    float* op = Cb + (rowbase + s) * 1024 + (size_t)head * 64;
    #pragma unroll
    for (int d = 0; d < 64; d += 4) {
        float4 o;
        o.x = ctx[d + 0] * inv; o.y = ctx[d + 1] * inv;
        o.z = ctx[d + 2] * inv; o.w = ctx[d + 3] * inv;
        *(float4*)(op + d) = o;
    }
}

// ---------------------------------------------------------------------------
// Token selection: column-softmax partial sums (deterministic two stage)
// ---------------------------------------------------------------------------
__global__ __launch_bounds__(256)
void colsum_part_kernel(const float* __restrict__ SC, float* __restrict__ P)
{
    int bid = blockIdx.x;            // b*128 + chunk
    int b = bid >> 7, chunk = bid & 127;
    int base = b * 8192 + chunk * 64;
    int k = threadIdx.x;
    float sum = 0.0f;
    for (int r = 0; r < 64; r++)
        sum += __expf(SC[(size_t)(base + r) * 256 + k]);
    P[(size_t)bid * 256 + k] = sum;
}

__global__ __launch_bounds__(256)
void colsum_reduce_kernel(const float* __restrict__ P, float* __restrict__ CS)
{
    int b = blockIdx.x;
    int k = threadIdx.x;
    float s = 0.0f;
    for (int c = 0; c < 128; c++)
        s += P[(size_t)(b * 128 + c) * 256 + k];
    CS[b * 256 + k] = s;
}

__global__ __launch_bounds__(256)
void wts_kernel(float* __restrict__ SC, const float* __restrict__ CS)
{
    int i4 = blockIdx.x * 256 + threadIdx.x;   // 1048576 total
    int e  = i4 << 2;
    int b  = e >> 21;
    int k  = e & 255;
    const float* cs = CS + b * 256 + k;
    float4 v = *(float4*)(SC + e);
    v.x = __expf(v.x) / cs[0];
    v.y = __expf(v.y) / cs[1];
    v.z = __expf(v.z) / cs[2];
    v.w = __expf(v.w) / cs[3];
    *(float4*)(SC + e) = v;
}

// SEL[b,k_,e] = sum_m WTS[b,m,k_] * FLAT[b,m,e]
// tile: 32 (k_) x 64 (e), inner loop m = 8192, grid (16,16), 256 threads
__global__ __launch_bounds__(256)
void gemm_sel(const float* __restrict__ W, const float* __restrict__ F,
              float* __restrict__ SEL)
{
    __shared__ float As[32][33];
    __shared__ float Bs[32][64];
    const int tid = threadIdx.x;
    const int n0 = blockIdx.x * 64;
    const int m2 = blockIdx.y * 32;
    const int b   = m2 >> 8;
    const int k0_ = m2 & 255;
    const float* Wb = W + (size_t)b * (8192 * 256);
    const float* Fb = F + (size_t)b * (8192 * 1024);
    const int tx = tid & 15, ty = tid >> 4;

    float acc[2][4];
    #pragma unroll
    for (int i = 0; i < 2; i++)
        #pragma unroll
        for (int j = 0; j < 4; j++) acc[i][j] = 0.0f;

    const int akk = tid >> 3, amm = (tid & 7) << 2;
    const int bkk = tid >> 4, bnn = (tid & 15) << 2;

    for (int kc = 0; kc < 8192; kc += 32) {
        float4 av  = *(const float4*)(Wb + (size_t)(kc + akk) * 256 + k0_ + amm);
        float4 bv0 = *(const float4*)(Fb + (size_t)(kc + bkk) * 1024 + n0 + bnn);
        float4 bv1 = *(const float4*)(Fb + (size_t)(kc + bkk + 16) * 1024 + n0 + bnn);
        As[akk][amm + 0] = av.x; As[akk][amm + 1] = av.y;
        As[akk][amm + 2] = av.z; As[akk][amm + 3] = av.w;
        *(float4*)&Bs[bkk][bnn]      = bv0;
        *(float4*)&Bs[bkk + 16][bnn] = bv1;
        __syncthreads();
        #pragma unroll
        for (int kk = 0; kk < 32; kk++) {
            float a0 = As[kk][ty * 2 + 0];
            float a1 = As[kk][ty * 2 + 1];
            float b0 = Bs[kk][tx * 4 + 0];
            float b1 = Bs[kk][tx * 4 + 1];
            float b2 = Bs[kk][tx * 4 + 2];
            float b3 = Bs[kk][tx * 4 + 3];
            acc[0][0] = fmaf(a0, b0, acc[0][0]);
            acc[0][1] = fmaf(a0, b1, acc[0][1]);
            acc[0][2] = fmaf(a0, b2, acc[0][2]);
            acc[0][3] = fmaf(a0, b3, acc[0][3]);
            acc[1][0] = fmaf(a1, b0, acc[1][0]);
            acc[1][1] = fmaf(a1, b1, acc[1][1]);
            acc[1][2] = fmaf(a1, b2, acc[1][2]);
            acc[1][3] = fmaf(a1, b3, acc[1][3]);
        }
        __syncthreads();
    }
    #pragma unroll
    for (int i = 0; i < 2; i++) {
        float* op = SEL + (size_t)(m2 + ty * 2 + i) * 1024 + n0 + tx * 4;
        float4 o = { acc[i][0], acc[i][1], acc[i][2], acc[i][3] };
        *(float4*)op = o;
    }
}

// multi-scale pooling into output [B, 256+128+64, 1024]
__global__ __launch_bounds__(256)
void pool_kernel(const float* __restrict__ SEL, float* __restrict__ out)
{
    int i4 = blockIdx.x * 256 + threadIdx.x;  // 229376 total
    int e  = i4 << 2;
    int row = e >> 10;          // b*448 + r
    int b = row / 448;
    int r = row - b * 448;
    int c = e & 1023;
    const float* sb = SEL + (size_t)b * (256 * 1024);
    float4 o;
    if (r < 256) {
        o = *(const float4*)(sb + (size_t)r * 1024 + c);
    } else if (r < 384) {
        int r2 = (r - 256) * 2;
        float4 x0 = *(const float4*)(sb + (size_t)r2 * 1024 + c);
        float4 x1 = *(const float4*)(sb + (size_t)(r2 + 1) * 1024 + c);
        o.x = 0.5f * (x0.x + x1.x); o.y = 0.5f * (x0.y + x1.y);
        o.z = 0.5f * (x0.z + x1.z); o.w = 0.5f * (x0.w + x1.w);
    } else {
        int r4 = (r - 384) * 4;
        float4 x0 = *(const float4*)(sb + (size_t)(r4 + 0) * 1024 + c);
        float4 x1 = *(const float4*)(sb + (size_t)(r4 + 1) * 1024 + c);
        float4 x2 = *(const float4*)(sb + (size_t)(r4 + 2) * 1024 + c);
        float4 x3 = *(const float4*)(sb + (size_t)(r4 + 3) * 1024 + c);
        o.x = 0.25f * (x0.x + x1.x + x2.x + x3.x);
        o.y = 0.25f * (x0.y + x1.y + x2.y + x3.y);
        o.z = 0.25f * (x0.z + x1.z + x2.z + x3.z);
        o.w = 0.25f * (x0.w + x1.w + x2.w + x3.w);
    }
    *(float4*)(out + e) = o;
}

// ---------------------------------------------------------------------------
extern "C" void kernel_launch(void* const* d_in, const int* in_sizes, int n_in,
                              void* d_out, int out_size, void* d_ws, size_t ws_size,
                              hipStream_t stream)
{
    const float* x    = (const float*)d_in[0];
    const float* wq   = (const float*)d_in[1];
    const float* bq   = (const float*)d_in[2];
    const float* wk   = (const float*)d_in[3];
    const float* bk   = (const float*)d_in[4];
    const float* wv   = (const float*)d_in[5];
    const float* bv   = (const float*)d_in[6];
    const float* wd   = (const float*)d_in[7];
    const float* bd   = (const float*)d_in[8];
    const float* rb   = (const float*)d_in[9];
    const float* selw = (const float*)d_in[10];
    const float* selb = (const float*)d_in[11];
    float* out = (float*)d_out;

    // workspace layout (floats), total 29,360,128 floats = 112 MB
    float* H = (float*)d_ws;          // 16,777,216  [16384 x 1024] running state
    float* Q = H + 16777216;          //  4,194,304  [4096 x 1024] chunk q / ctx
    float* K = Q + 4194304;           //  4,194,304  [4096 x 1024] chunk k
    float* V = K + 4194304;           //  4,194,304  [4096 x 1024] chunk v
    // selection aliases (used after all attention stages complete)
    float* SC   = Q;                  //  4,194,304  [16384 x 256]
    float* SEL  = K;                  //    524,288  [2 x 256 x 1024]
    float* PART = K + 524288;         //     65,536
    float* CSUM = K + 524288 + 65536; //        512

    const dim3 blk(256);
    const dim3 g_gemm(8, 32);   // 1024 cols x 4096 rows per chunk

    for (int a = 0; a < 4; a++) {
        const float* hin = (a == 0) ? x : H;
        const int mi = (a & 1);   // temporal gather/scatter
        const size_t wo = (size_t)a * 1024 * 1024;
        const int bo = a * 1024;
        const float* rba = rb + (size_t)a * 1023 * 16;
        for (int c = 0; c < 4; c++) {
            const int mo = c * 4096;
            gemm_rm<<<g_gemm, blk, 0, stream>>>(hin, wq + wo, bq + bo, Q,
                                                1024, 1024, 1024, mi, 0, mo, 0);
            gemm_rm<<<g_gemm, blk, 0, stream>>>(hin, wk + wo, bk + bo, K,
                                                1024, 1024, 1024, mi, 0, mo, 0);
            gemm_rm<<<g_gemm, blk, 0, stream>>>(hin, wv + wo, bv + bo, V,
                                                1024, 1024, 1024, mi, 0, mo, 0);
            if (mi == 0)
                attn_kernel<256, 1><<<dim3(16, 16), blk, 0, stream>>>(Q, K, V, rba, Q);
            else
                attn_kernel<32, 8><<<dim3(128, 2), blk, 0, stream>>>(Q, K, V, rba, Q);
            // in-place H update: this chunk's output rows == this chunk's
            // input rows (same map), disjoint from other chunks' reads.
            gemm_rm<<<g_gemm, blk, 0, stream>>>(Q, wd + wo, bd + bo, H,
                                                1024, 1024, 1024, 0, mi, 0, mo);
        }
    }

    // token selection
    gemm_rm<<<dim3(2, 128), blk, 0, stream>>>(H, selw, selb, SC,
                                              256, 256, 1024, 0, 0, 0, 0);
    colsum_part_kernel<<<256, blk, 0, stream>>>(SC, PART);
    colsum_reduce_kernel<<<2, blk, 0, stream>>>(PART, CSUM);
    wts_kernel<<<4096, blk, 0, stream>>>(SC, CSUM);
    gemm_sel<<<dim3(16, 16), blk, 0, stream>>>(SC, H, SEL);
    pool_kernel<<<896, blk, 0, stream>>>(SEL, out);
}

// Round 3
// 8735.064 us; speedup vs baseline: 1.3968x; 1.3968x over previous
//
#include <hip/hip_runtime.h>
#include <stdint.h>

// Problem constants
// B=2, T=32, N=256, E=1024, H=16, D=64, L=2, K=256, MAXLEN=512
// tokens = B*T*N = 16384

__device__ __forceinline__ int tmap_dev(int m) {
    // temporal token m = (b*N+n)*T + t  ->  flat row (b*T+t)*N + n
    int bx = m >> 5;        // m / T (T=32)
    int s  = m & 31;        // t
    int b  = bx >> 8;       // bx / N (N=256)
    int n  = bx & 255;
    return (((b << 5) + s) << 8) + n;   // (b*32+s)*256 + n
}

// ---------------------------------------------------------------------------
// Generic row-major fp32 GEMM: C[m, n] = sum_k A[rin(m)][k] * B[k*ldb+n] + bias[n]
// tile 128x128, BK=16, 256 threads, 8x8 per thread.
// ---------------------------------------------------------------------------
__global__ __launch_bounds__(256)
void gemm_rm(const float* __restrict__ A, const float* __restrict__ Bw,
             const float* __restrict__ bias, float* __restrict__ C,
             int ldb, int ldc, int Kd, int map_in, int map_out,
             int m_off_in, int m_off_out)
{
    __shared__ float As[16][132];
    __shared__ float Bs[16][128];
    const int tid = threadIdx.x;
    const int n0 = blockIdx.x * 128;
    const int m0 = blockIdx.y * 128;
    const int tx = tid & 15, ty = tid >> 4;

    float acc[8][8];
    #pragma unroll
    for (int i = 0; i < 8; i++)
        #pragma unroll
        for (int j = 0; j < 8; j++) acc[i][j] = 0.0f;

    const int r0  = tid >> 2;            // 0..63
    const int r1  = r0 + 64;
    const int kc0 = (tid & 3) << 2;      // 0,4,8,12
    const int gin0 = m_off_in + m0 + r0;
    const int gin1 = m_off_in + m0 + r1;
    const int gr0 = map_in ? tmap_dev(gin0) : gin0;
    const int gr1 = map_in ? tmap_dev(gin1) : gin1;
    const float* arow0 = A + (size_t)gr0 * Kd;
    const float* arow1 = A + (size_t)gr1 * Kd;

    const int br0 = tid >> 5;            // 0..7
    const int bc0 = (tid & 31) << 2;     // 0..124

    for (int k0 = 0; k0 < Kd; k0 += 16) {
        float4 a0 = *(const float4*)(arow0 + k0 + kc0);
        float4 a1 = *(const float4*)(arow1 + k0 + kc0);
        float4 b0 = *(const float4*)(Bw + (size_t)(k0 + br0) * ldb + n0 + bc0);
        float4 b1 = *(const float4*)(Bw + (size_t)(k0 + br0 + 8) * ldb + n0 + bc0);

        As[kc0 + 0][r0] = a0.x; As[kc0 + 1][r0] = a0.y;
        As[kc0 + 2][r0] = a0.z; As[kc0 + 3][r0] = a0.w;
        As[kc0 + 0][r1] = a1.x; As[kc0 + 1][r1] = a1.y;
        As[kc0 + 2][r1] = a1.z; As[kc0 + 3][r1] = a1.w;
        *(float4*)&Bs[br0][bc0]     = b0;
        *(float4*)&Bs[br0 + 8][bc0] = b1;
        __syncthreads();

        #pragma unroll
        for (int kk = 0; kk < 16; kk++) {
            float a[8], b[8];
            #pragma unroll
            for (int i = 0; i < 8; i++) a[i] = As[kk][ty * 8 + i];
            #pragma unroll
            for (int j = 0; j < 8; j++) b[j] = Bs[kk][tx * 8 + j];
            #pragma unroll
            for (int i = 0; i < 8; i++)
                #pragma unroll
                for (int j = 0; j < 8; j++)
                    acc[i][j] = fmaf(a[i], b[j], acc[i][j]);
        }
        __syncthreads();
    }

    #pragma unroll
    for (int i = 0; i < 8; i++) {
        int gm = m_off_out + m0 + ty * 8 + i;
        int row = map_out ? tmap_dev(gm) : gm;
        float* cp = C + (size_t)row * ldc + n0 + tx * 8;
        const float* bp = bias + n0 + tx * 8;
        float4 v0, v1;
        v0.x = acc[i][0] + bp[0]; v0.y = acc[i][1] + bp[1];
        v0.z = acc[i][2] + bp[2]; v0.w = acc[i][3] + bp[3];
        v1.x = acc[i][4] + bp[4]; v1.y = acc[i][5] + bp[5];
        v1.z = acc[i][6] + bp[6]; v1.w = acc[i][7] + bp[7];
        *(float4*)cp       = v0;
        *(float4*)(cp + 4) = v1;
    }
}

// ---------------------------------------------------------------------------
// Merged Q/K/V projection: blockIdx.z selects weight/bias/output.
// All dims fixed at 1024. Same tile structure as gemm_rm.
// grid: (8, Mtile/128, 3)
// ---------------------------------------------------------------------------
__global__ __launch_bounds__(256)
void gemm_qkv3(const float* __restrict__ A,
               const float* __restrict__ W0, const float* __restrict__ W1,
               const float* __restrict__ W2,
               const float* __restrict__ b0_, const float* __restrict__ b1_,
               const float* __restrict__ b2_,
               float* __restrict__ C0, float* __restrict__ C1,
               float* __restrict__ C2,
               int map_in, int m_off_in)
{
    const float* Bw; const float* bias; float* C;
    if (blockIdx.z == 0)      { Bw = W0; bias = b0_; C = C0; }
    else if (blockIdx.z == 1) { Bw = W1; bias = b1_; C = C1; }
    else                      { Bw = W2; bias = b2_; C = C2; }

    __shared__ float As[16][132];
    __shared__ float Bs[16][128];
    const int tid = threadIdx.x;
    const int n0 = blockIdx.x * 128;
    const int m0 = blockIdx.y * 128;
    const int tx = tid & 15, ty = tid >> 4;

    float acc[8][8];
    #pragma unroll
    for (int i = 0; i < 8; i++)
        #pragma unroll
        for (int j = 0; j < 8; j++) acc[i][j] = 0.0f;

    const int r0  = tid >> 2;
    const int r1  = r0 + 64;
    const int kc0 = (tid & 3) << 2;
    const int gin0 = m_off_in + m0 + r0;
    const int gin1 = m_off_in + m0 + r1;
    const int gr0 = map_in ? tmap_dev(gin0) : gin0;
    const int gr1 = map_in ? tmap_dev(gin1) : gin1;
    const float* arow0 = A + (size_t)gr0 * 1024;
    const float* arow1 = A + (size_t)gr1 * 1024;

    const int br0 = tid >> 5;
    const int bc0 = (tid & 31) << 2;

    for (int k0 = 0; k0 < 1024; k0 += 16) {
        float4 a0 = *(const float4*)(arow0 + k0 + kc0);
        float4 a1 = *(const float4*)(arow1 + k0 + kc0);
        float4 b0 = *(const float4*)(Bw + (size_t)(k0 + br0) * 1024 + n0 + bc0);
        float4 b1 = *(const float4*)(Bw + (size_t)(k0 + br0 + 8) * 1024 + n0 + bc0);

        As[kc0 + 0][r0] = a0.x; As[kc0 + 1][r0] = a0.y;
        As[kc0 + 2][r0] = a0.z; As[kc0 + 3][r0] = a0.w;
        As[kc0 + 0][r1] = a1.x; As[kc0 + 1][r1] = a1.y;
        As[kc0 + 2][r1] = a1.z; As[kc0 + 3][r1] = a1.w;
        *(float4*)&Bs[br0][bc0]     = b0;
        *(float4*)&Bs[br0 + 8][bc0] = b1;
        __syncthreads();

        #pragma unroll
        for (int kk = 0; kk < 16; kk++) {
            float a[8], b[8];
            #pragma unroll
            for (int i = 0; i < 8; i++) a[i] = As[kk][ty * 8 + i];
            #pragma unroll
            for (int j = 0; j < 8; j++) b[j] = Bs[kk][tx * 8 + j];
            #pragma unroll
            for (int i = 0; i < 8; i++)
                #pragma unroll
                for (int j = 0; j < 8; j++)
                    acc[i][j] = fmaf(a[i], b[j], acc[i][j]);
        }
        __syncthreads();
    }

    #pragma unroll
    for (int i = 0; i < 8; i++) {
        int gm = m0 + ty * 8 + i;
        float* cp = C + (size_t)gm * 1024 + n0 + tx * 8;
        const float* bp = bias + n0 + tx * 8;
        float4 v0, v1;
        v0.x = acc[i][0] + bp[0]; v0.y = acc[i][1] + bp[1];
        v0.z = acc[i][2] + bp[2]; v0.w = acc[i][3] + bp[3];
        v1.x = acc[i][4] + bp[4]; v1.y = acc[i][5] + bp[5];
        v1.z = acc[i][6] + bp[6]; v1.w = acc[i][7] + bp[7];
        *(float4*)cp       = v0;
        *(float4*)(cp + 4) = v1;
    }
}

// ---------------------------------------------------------------------------
// Spatial attention, S=256. One block per (frame, head); 256 threads = rows.
// Single pass, NO max subtraction: scores = q.k/8 + bias have |sc| <~ 6
// (q,k elem std ~0.64 -> dot/8 std ~0.4; bias std 0.02), exp() safe in fp32
// with ~35 sigma margin to overflow; softmax is shift-invariant.
// K/V j-tiled (64 rows) through LDS; rel-bias diagonal (511 vals) in LDS.
// Cb may alias Qb (q read to regs before first barrier; disjoint regions).
// grid: (frames, 16)
// ---------------------------------------------------------------------------
__global__ __launch_bounds__(256, 2)
void attn_s(const float* __restrict__ Qb, const float* __restrict__ Kb,
            const float* __restrict__ Vb, const float* __restrict__ RB,
            float* __restrict__ Cb, int frame_off)
{
    __shared__ float Kt[64 * 64];
    __shared__ float Vt[64 * 64];
    __shared__ float Bt[512];
    const int tid = threadIdx.x;
    const int frame = frame_off + blockIdx.x;
    const int head = blockIdx.y;
    const int s = tid;
    const size_t rowbase = (size_t)frame * 256;

    // q into registers (before any barrier; Cb may alias Qb)
    float q[64];
    {
        const float* qp = Qb + (rowbase + s) * 1024 + (size_t)head * 64;
        #pragma unroll
        for (int l = 0; l < 16; l++) {
            float4 t4 = *(const float4*)(qp + (l << 2));
            q[l * 4 + 0] = t4.x; q[l * 4 + 1] = t4.y;
            q[l * 4 + 2] = t4.z; q[l * 4 + 3] = t4.w;
        }
    }
    // bias diagonal: rb rows 256..766, element `head` -> Bt[0..510]
    #pragma unroll
    for (int l = 0; l < 2; l++) {
        int idx = tid + l * 256;
        if (idx < 511) Bt[idx] = RB[(size_t)(256 + idx) * 16 + head];
    }

    float ctx[64];
    #pragma unroll
    for (int d = 0; d < 64; d++) ctx[d] = 0.0f;
    float lsum = 0.0f;

    for (int jt = 0; jt < 4; jt++) {
        __syncthreads();   // protect LDS reuse across tiles (also orders bias)
        // stage K/V tile: 4096 floats each; 4 float4 per thread each
        #pragma unroll
        for (int l = 0; l < 4; l++) {
            int e = (tid + l * 256) << 2;
            int j = e >> 6, d = e & 63;
            size_t src = (rowbase + jt * 64 + j) * 1024 + (size_t)head * 64 + d;
            *(float4*)&Kt[e] = *(const float4*)(Kb + src);
            *(float4*)&Vt[e] = *(const float4*)(Vb + src);
        }
        __syncthreads();

        const int bofs = jt * 64 - s + 255;
        for (int j = 0; j < 64; j++) {
            const float* kr = Kt + (j << 6);
            float d0 = 0.f, d1 = 0.f, d2 = 0.f, d3 = 0.f;
            #pragma unroll
            for (int d = 0; d < 64; d += 4) {
                d0 = fmaf(q[d + 0], kr[d + 0], d0);
                d1 = fmaf(q[d + 1], kr[d + 1], d1);
                d2 = fmaf(q[d + 2], kr[d + 2], d2);
                d3 = fmaf(q[d + 3], kr[d + 3], d3);
            }
            float sc = ((d0 + d1) + (d2 + d3)) * 0.125f + Bt[bofs + j];
            float p = __expf(sc);
            lsum += p;
            const float* vr = Vt + (j << 6);
            #pragma unroll
            for (int d = 0; d < 64; d += 4) {
                ctx[d + 0] = fmaf(p, vr[d + 0], ctx[d + 0]);
                ctx[d + 1] = fmaf(p, vr[d + 1], ctx[d + 1]);
                ctx[d + 2] = fmaf(p, vr[d + 2], ctx[d + 2]);
                ctx[d + 3] = fmaf(p, vr[d + 3], ctx[d + 3]);
            }
        }
    }

    float inv = 1.0f / lsum;
    float* op = Cb + (rowbase + s) * 1024 + (size_t)head * 64;
    #pragma unroll
    for (int d = 0; d < 64; d += 4) {
        float4 o;
        o.x = ctx[d + 0] * inv; o.y = ctx[d + 1] * inv;
        o.z = ctx[d + 2] * inv; o.w = ctx[d + 3] * inv;
        *(float4*)(op + d) = o;
    }
}

// ---------------------------------------------------------------------------
// Temporal attention, S=32. Block = 256 threads = 8 (head) units x 32 rows.
// No LDS: K/V rows read from global (broadcast within unit, L1/L2 resident).
// Single pass, no max subtraction (same magnitude argument).
// Cb may alias Qb. grid: (Bx, 2)
// ---------------------------------------------------------------------------
__global__ __launch_bounds__(256, 2)
void attn_t(const float* __restrict__ Qb, const float* __restrict__ Kb,
            const float* __restrict__ Vb, const float* __restrict__ RB,
            float* __restrict__ Cb, int bx_off)
{
    const int tid = threadIdx.x;
    const int bx = bx_off + blockIdx.x;
    const int head = blockIdx.y * 8 + (tid >> 5);
    const int s = tid & 31;
    const size_t rowbase = (size_t)bx * 32;

    float q[64];
    {
        const float* qp = Qb + (rowbase + s) * 1024 + (size_t)head * 64;
        #pragma unroll
        for (int l = 0; l < 16; l++) {
            float4 t4 = *(const float4*)(qp + (l << 2));
            q[l * 4 + 0] = t4.x; q[l * 4 + 1] = t4.y;
            q[l * 4 + 2] = t4.z; q[l * 4 + 3] = t4.w;
        }
    }

    float ctx[64];
    #pragma unroll
    for (int d = 0; d < 64; d++) ctx[d] = 0.0f;
    float lsum = 0.0f;
    const float* kbase = Kb + rowbase * 1024 + (size_t)head * 64;
    const float* vbase = Vb + rowbase * 1024 + (size_t)head * 64;
    const float* rbp = RB + (size_t)(511 - s) * 16 + head;

    for (int j = 0; j < 32; j++) {
        const float* kr = kbase + (size_t)j * 1024;
        float d0 = 0.f, d1 = 0.f, d2 = 0.f, d3 = 0.f;
        #pragma unroll
        for (int d = 0; d < 64; d += 4) {
            float4 k4 = *(const float4*)(kr + d);
            d0 = fmaf(q[d + 0], k4.x, d0);
            d1 = fmaf(q[d + 1], k4.y, d1);
            d2 = fmaf(q[d + 2], k4.z, d2);
            d3 = fmaf(q[d + 3], k4.w, d3);
        }
        float sc = ((d0 + d1) + (d2 + d3)) * 0.125f + rbp[(size_t)j * 16];
        float p = __expf(sc);
        lsum += p;
        const float* vr = vbase + (size_t)j * 1024;
        #pragma unroll
        for (int d = 0; d < 64; d += 4) {
            float4 v4 = *(const float4*)(vr + d);
            ctx[d + 0] = fmaf(p, v4.x, ctx[d + 0]);
            ctx[d + 1] = fmaf(p, v4.y, ctx[d + 1]);
            ctx[d + 2] = fmaf(p, v4.z, ctx[d + 2]);
            ctx[d + 3] = fmaf(p, v4.w, ctx[d + 3]);
        }
    }

    float inv = 1.0f / lsum;
    float* op = Cb + (rowbase + s) * 1024 + (size_t)head * 64;
    #pragma unroll
    for (int d = 0; d < 64; d += 4) {
        float4 o;
        o.x = ctx[d + 0] * inv; o.y = ctx[d + 1] * inv;
        o.z = ctx[d + 2] * inv; o.w = ctx[d + 3] * inv;
        *(float4*)(op + d) = o;
    }
}

// ---------------------------------------------------------------------------
// Token selection: column-softmax partial sums (deterministic two stage)
// ---------------------------------------------------------------------------
__global__ __launch_bounds__(256)
void colsum_part_kernel(const float* __restrict__ SC, float* __restrict__ P)
{
    int bid = blockIdx.x;
    int b = bid >> 7, chunk = bid & 127;
    int base = b * 8192 + chunk * 64;
    int k = threadIdx.x;
    float sum = 0.0f;
    for (int r = 0; r < 64; r++)
        sum += __expf(SC[(size_t)(base + r) * 256 + k]);
    P[(size_t)bid * 256 + k] = sum;
}

__global__ __launch_bounds__(256)
void colsum_reduce_kernel(const float* __restrict__ P, float* __restrict__ CS)
{
    int b = blockIdx.x;
    int k = threadIdx.x;
    float s = 0.0f;
    for (int c = 0; c < 128; c++)
        s += P[(size_t)(b * 128 + c) * 256 + k];
    CS[b * 256 + k] = s;
}

__global__ __launch_bounds__(256)
void wts_kernel(float* __restrict__ SC, const float* __restrict__ CS)
{
    int i4 = blockIdx.x * 256 + threadIdx.x;
    int e  = i4 << 2;
    int b  = e >> 21;
    int k  = e & 255;
    const float* cs = CS + b * 256 + k;
    float4 v = *(float4*)(SC + e);
    v.x = __expf(v.x) / cs[0];
    v.y = __expf(v.y) / cs[1];
    v.z = __expf(v.z) / cs[2];
    v.w = __expf(v.w) / cs[3];
    *(float4*)(SC + e) = v;
}

// SEL[b,k_,e] = sum_m WTS[b,m,k_] * FLAT[b,m,e]
__global__ __launch_bounds__(256)
void gemm_sel(const float* __restrict__ W, const float* __restrict__ F,
              float* __restrict__ SEL)
{
    __shared__ float As[32][33];
    __shared__ float Bs[32][64];
    const int tid = threadIdx.x;
    const int n0 = blockIdx.x * 64;
    const int m2 = blockIdx.y * 32;
    const int b   = m2 >> 8;
    const int k0_ = m2 & 255;
    const float* Wb = W + (size_t)b * (8192 * 256);
    const float* Fb = F + (size_t)b * (8192 * 1024);
    const int tx = tid & 15, ty = tid >> 4;

    float acc[2][4];
    #pragma unroll
    for (int i = 0; i < 2; i++)
        #pragma unroll
        for (int j = 0; j < 4; j++) acc[i][j] = 0.0f;

    const int akk = tid >> 3, amm = (tid & 7) << 2;
    const int bkk = tid >> 4, bnn = (tid & 15) << 2;

    for (int kc = 0; kc < 8192; kc += 32) {
        float4 av  = *(const float4*)(Wb + (size_t)(kc + akk) * 256 + k0_ + amm);
        float4 bv0 = *(const float4*)(Fb + (size_t)(kc + bkk) * 1024 + n0 + bnn);
        float4 bv1 = *(const float4*)(Fb + (size_t)(kc + bkk + 16) * 1024 + n0 + bnn);
        As[akk][amm + 0] = av.x; As[akk][amm + 1] = av.y;
        As[akk][amm + 2] = av.z; As[akk][amm + 3] = av.w;
        *(float4*)&Bs[bkk][bnn]      = bv0;
        *(float4*)&Bs[bkk + 16][bnn] = bv1;
        __syncthreads();
        #pragma unroll
        for (int kk = 0; kk < 32; kk++) {
            float a0 = As[kk][ty * 2 + 0];
            float a1 = As[kk][ty * 2 + 1];
            float b0 = Bs[kk][tx * 4 + 0];
            float b1 = Bs[kk][tx * 4 + 1];
            float b2 = Bs[kk][tx * 4 + 2];
            float b3 = Bs[kk][tx * 4 + 3];
            acc[0][0] = fmaf(a0, b0, acc[0][0]);
            acc[0][1] = fmaf(a0, b1, acc[0][1]);
            acc[0][2] = fmaf(a0, b2, acc[0][2]);
            acc[0][3] = fmaf(a0, b3, acc[0][3]);
            acc[1][0] = fmaf(a1, b0, acc[1][0]);
            acc[1][1] = fmaf(a1, b1, acc[1][1]);
            acc[1][2] = fmaf(a1, b2, acc[1][2]);
            acc[1][3] = fmaf(a1, b3, acc[1][3]);
        }
        __syncthreads();
    }
    #pragma unroll
    for (int i = 0; i < 2; i++) {
        float* op = SEL + (size_t)(m2 + ty * 2 + i) * 1024 + n0 + tx * 4;
        float4 o = { acc[i][0], acc[i][1], acc[i][2], acc[i][3] };
        *(float4*)op = o;
    }
}

// multi-scale pooling into output [B, 256+128+64, 1024]
__global__ __launch_bounds__(256)
void pool_kernel(const float* __restrict__ SEL, float* __restrict__ out)
{
    int i4 = blockIdx.x * 256 + threadIdx.x;
    int e  = i4 << 2;
    int row = e >> 10;
    int b = row / 448;
    int r = row - b * 448;
    int c = e & 1023;
    const float* sb = SEL + (size_t)b * (256 * 1024);
    float4 o;
    if (r < 256) {
        o = *(const float4*)(sb + (size_t)r * 1024 + c);
    } else if (r < 384) {
        int r2 = (r - 256) * 2;
        float4 x0 = *(const float4*)(sb + (size_t)r2 * 1024 + c);
        float4 x1 = *(const float4*)(sb + (size_t)(r2 + 1) * 1024 + c);
        o.x = 0.5f * (x0.x + x1.x); o.y = 0.5f * (x0.y + x1.y);
        o.z = 0.5f * (x0.z + x1.z); o.w = 0.5f * (x0.w + x1.w);
    } else {
        int r4 = (r - 384) * 4;
        float4 x0 = *(const float4*)(sb + (size_t)(r4 + 0) * 1024 + c);
        float4 x1 = *(const float4*)(sb + (size_t)(r4 + 1) * 1024 + c);
        float4 x2 = *(const float4*)(sb + (size_t)(r4 + 2) * 1024 + c);
        float4 x3 = *(const float4*)(sb + (size_t)(r4 + 3) * 1024 + c);
        o.x = 0.25f * (x0.x + x1.x + x2.x + x3.x);
        o.y = 0.25f * (x0.y + x1.y + x2.y + x3.y);
        o.z = 0.25f * (x0.z + x1.z + x2.z + x3.z);
        o.w = 0.25f * (x0.w + x1.w + x2.w + x3.w);
    }
    *(float4*)(out + e) = o;
}

// ---------------------------------------------------------------------------
extern "C" void kernel_launch(void* const* d_in, const int* in_sizes, int n_in,
                              void* d_out, int out_size, void* d_ws, size_t ws_size,
                              hipStream_t stream)
{
    const float* x    = (const float*)d_in[0];
    const float* wq   = (const float*)d_in[1];
    const float* bq   = (const float*)d_in[2];
    const float* wk   = (const float*)d_in[3];
    const float* bk   = (const float*)d_in[4];
    const float* wv   = (const float*)d_in[5];
    const float* bv   = (const float*)d_in[6];
    const float* wd   = (const float*)d_in[7];
    const float* bd   = (const float*)d_in[8];
    const float* rb   = (const float*)d_in[9];
    const float* selw = (const float*)d_in[10];
    const float* selb = (const float*)d_in[11];
    float* out = (float*)d_out;

    const dim3 blk(256);
    const bool full = ws_size >= (size_t)268435456;  // 256 MB

    if (full) {
        // H | Q | K | V, each 16,777,216 floats (64 MB)
        float* H = (float*)d_ws;
        float* Q = H + 16777216;
        float* K = Q + 16777216;
        float* V = K + 16777216;
        float* SC   = Q;                    // aliases after attention done
        float* SEL  = K;
        float* PART = K + 524288;
        float* CSUM = K + 524288 + 65536;

        for (int a = 0; a < 4; a++) {
            const float* hin = (a == 0) ? x : H;
            const int mi = (a & 1);
            const size_t wo = (size_t)a * 1024 * 1024;
            const int bo = a * 1024;
            const float* rba = rb + (size_t)a * 1023 * 16;
            gemm_qkv3<<<dim3(8, 128, 3), blk, 0, stream>>>(
                hin, wq + wo, wk + wo, wv + wo, bq + bo, bk + bo, bv + bo,
                Q, K, V, mi, 0);
            if (mi == 0)
                attn_s<<<dim3(64, 16), blk, 0, stream>>>(Q, K, V, rba, Q, 0);
            else
                attn_t<<<dim3(512, 2), blk, 0, stream>>>(Q, K, V, rba, Q, 0);
            gemm_rm<<<dim3(8, 128), blk, 0, stream>>>(Q, wd + wo, bd + bo, H,
                                                      1024, 1024, 1024, 0, mi, 0, 0);
        }

        gemm_rm<<<dim3(2, 128), blk, 0, stream>>>(H, selw, selb, SC,
                                                  256, 256, 1024, 0, 0, 0, 0);
        colsum_part_kernel<<<256, blk, 0, stream>>>(SC, PART);
        colsum_reduce_kernel<<<2, blk, 0, stream>>>(PART, CSUM);
        wts_kernel<<<4096, blk, 0, stream>>>(SC, CSUM);
        gemm_sel<<<dim3(16, 16), blk, 0, stream>>>(SC, H, SEL);
        pool_kernel<<<896, blk, 0, stream>>>(SEL, out);
    } else {
        // chunked fallback: H (64MB) + Q/K/V chunk buffers (16MB each)
        float* H = (float*)d_ws;
        float* Q = H + 16777216;
        float* K = Q + 4194304;
        float* V = K + 4194304;
        float* SC   = Q;
        float* SEL  = K;
        float* PART = K + 524288;
        float* CSUM = K + 524288 + 65536;

        for (int a = 0; a < 4; a++) {
            const float* hin = (a == 0) ? x : H;
            const int mi = (a & 1);
            const size_t wo = (size_t)a * 1024 * 1024;
            const int bo = a * 1024;
            const float* rba = rb + (size_t)a * 1023 * 16;
            for (int c = 0; c < 4; c++) {
                const int mo = c * 4096;
                gemm_qkv3<<<dim3(8, 32, 3), blk, 0, stream>>>(
                    hin, wq + wo, wk + wo, wv + wo, bq + bo, bk + bo, bv + bo,
                    Q, K, V, mi, mo);
                if (mi == 0)
                    attn_s<<<dim3(16, 16), blk, 0, stream>>>(Q, K, V, rba, Q, 0);
                else
                    attn_t<<<dim3(128, 2), blk, 0, stream>>>(Q, K, V, rba, Q, 0);
                gemm_rm<<<dim3(8, 32), blk, 0, stream>>>(Q, wd + wo, bd + bo, H,
                                                         1024, 1024, 1024, 0, mi, 0, mo);
            }
        }

        gemm_rm<<<dim3(2, 128), blk, 0, stream>>>(H, selw, selb, SC,
                                                  256, 256, 1024, 0, 0, 0, 0);
        colsum_part_kernel<<<256, blk, 0, stream>>>(SC, PART);
        colsum_reduce_kernel<<<2, blk, 0, stream>>>(PART, CSUM);
        wts_kernel<<<4096, blk, 0, stream>>>(SC, CSUM);
        gemm_sel<<<dim3(16, 16), blk, 0, stream>>>(SC, H, SEL);
        pool_kernel<<<896, blk, 0, stream>>>(SEL, out);
    }
}

// Round 4
// 3725.125 us; speedup vs baseline: 3.2753x; 2.3449x over previous
//
#include <hip/hip_runtime.h>
#include <stdint.h>

// Problem constants: B=2, T=32, N=256, E=1024, H=16, D=64, L=2, K=256, MAXLEN=512
// tokens = B*T*N = 16384, processed in 2 chunks of 8192 rows.

using f16x8 = __attribute__((ext_vector_type(8))) _Float16;
using f16x4 = __attribute__((ext_vector_type(4))) _Float16;
using f32x4 = __attribute__((ext_vector_type(4))) float;

__device__ __forceinline__ int tmap_dev(int m) {
    // temporal token m = (b*N+n)*T + t  ->  flat row (b*T+t)*N + n
    int bx = m >> 5;
    int s  = m & 31;
    int b  = bx >> 8;
    int n  = bx & 255;
    return (((b << 5) + s) << 8) + n;
}

// async global->LDS 16B (wave-uniform base + lane*16 on the LDS side)
__device__ __forceinline__ void load16(const _Float16* g, _Float16* l)
{
    __builtin_amdgcn_global_load_lds(
        (const __attribute__((address_space(1))) unsigned int*)g,
        (__attribute__((address_space(3))) unsigned int*)l,
        16, 0, 0);
}

// ---------------------------------------------------------------------------
// Activation fp32 -> split f16 hi/lo, with optional temporal row gather.
// src rows are GLOBAL (16384); dst rows chunk-local (8192). grid 4096 x 256.
// ---------------------------------------------------------------------------
__global__ __launch_bounds__(256)
void conv_act(const float* __restrict__ src, _Float16* __restrict__ dh,
              _Float16* __restrict__ dl, int map_in, int m_off)
{
    int idx = blockIdx.x * 256 + threadIdx.x;
    int e = idx << 3;
    int ml = e >> 10, col = e & 1023;
    int gm = m_off + ml;
    int row = map_in ? tmap_dev(gm) : gm;
    const float* s = src + (size_t)row * 1024 + col;
    float4 a = *(const float4*)s;
    float4 b = *(const float4*)(s + 4);
    float vv[8] = {a.x, a.y, a.z, a.w, b.x, b.y, b.z, b.w};
    f16x8 vh, vl;
    #pragma unroll
    for (int r = 0; r < 8; r++) {
        _Float16 h = (_Float16)vv[r];
        vh[r] = h;
        vl[r] = (_Float16)(vv[r] - (float)h);
    }
    *(f16x8*)(dh + (size_t)ml * 1024 + col) = vh;
    *(f16x8*)(dl + (size_t)ml * 1024 + col) = vl;
}

// ---------------------------------------------------------------------------
// Weight fp32 [1024][ncols] -> transposed split f16 Th/Tl [ncols][1024].
// grid (ncols/64, 16), 256 threads, LDS 64x65 transpose tile.
// ---------------------------------------------------------------------------
__global__ __launch_bounds__(256)
void conv_wT(const float* __restrict__ W, _Float16* __restrict__ Th,
             _Float16* __restrict__ Tl, int ncols)
{
    __shared__ float Ls[64][65];
    const int n0 = blockIdx.x * 64, k0 = blockIdx.y * 64;
    const int t = threadIdx.x;
    const int kk = t >> 4, nn = (t & 15) << 2;
    #pragma unroll
    for (int i = 0; i < 4; i++) {
        float4 v = *(const float4*)(W + (size_t)(k0 + kk + 16 * i) * ncols + n0 + nn);
        Ls[kk + 16 * i][nn + 0] = v.x; Ls[kk + 16 * i][nn + 1] = v.y;
        Ls[kk + 16 * i][nn + 2] = v.z; Ls[kk + 16 * i][nn + 3] = v.w;
    }
    __syncthreads();
    const int nl = t >> 4, kc = (t & 15) << 2;
    #pragma unroll
    for (int i = 0; i < 4; i++) {
        int n = nl + 16 * i;
        f16x4 hh, ll;
        #pragma unroll
        for (int c = 0; c < 4; c++) {
            float v = Ls[kc + c][n];
            _Float16 h = (_Float16)v;
            hh[c] = h;
            ll[c] = (_Float16)(v - (float)h);
        }
        *(f16x4*)(Th + (size_t)(n0 + n) * 1024 + k0 + kc) = hh;
        *(f16x4*)(Tl + (size_t)(n0 + n) * 1024 + k0 + kc) = ll;
    }
}

// ---------------------------------------------------------------------------
// Split-f16 MFMA GEMM core: C = (Ah+Al)@(Wh+Wl)^T + bias  (lo*lo dropped).
// A: [8192][1024] f16 hi/lo (chunk-local rows). W: transposed [N][1024] hi/lo.
// Tile 128x128, BK=32, 256 threads (4 waves, 2x2 of 64x64).
// ---------------------------------------------------------------------------
__device__ __forceinline__ void gemm_core(
    const _Float16* __restrict__ Ah, const _Float16* __restrict__ Al,
    const _Float16* __restrict__ Wh, const _Float16* __restrict__ Wl,
    const float* __restrict__ bias, float* __restrict__ C,
    int ldc, int map_out, int m_off_out, int n0, int m0)
{
    __shared__ _Float16 sAh[4096], sAl[4096], sBh[4096], sBl[4096];
    const int tid = threadIdx.x;
    const int lane = tid & 63;
    const int wv = tid >> 6;
    const int fm = (wv >> 1) << 6;
    const int fn = (wv & 1) << 6;
    const int lm = lane & 15, lq = lane >> 4;

    f32x4 acc[4][4] = {};

    // staging: thread t covers LDS f16 elems [t*8, t*8+8) (round0) and +2048 (round1)
    const int srow = tid >> 2;           // 0..63
    const int skc  = (tid & 3) << 3;     // 0,8,16,24
    const _Float16* gA0 = Ah + (size_t)(m0 + srow) * 1024 + skc;
    const _Float16* gA1 = Al + (size_t)(m0 + srow) * 1024 + skc;
    const _Float16* gB0 = Wh + (size_t)(n0 + srow) * 1024 + skc;
    const _Float16* gB1 = Wl + (size_t)(n0 + srow) * 1024 + skc;
    const int lo = tid << 3;

    for (int k0 = 0; k0 < 1024; k0 += 32) {
        load16(gA0 + k0,         sAh + lo);
        load16(gA0 + k0 + 65536, sAh + lo + 2048);
        load16(gA1 + k0,         sAl + lo);
        load16(gA1 + k0 + 65536, sAl + lo + 2048);
        load16(gB0 + k0,         sBh + lo);
        load16(gB0 + k0 + 65536, sBh + lo + 2048);
        load16(gB1 + k0,         sBl + lo);
        load16(gB1 + k0 + 65536, sBl + lo + 2048);
        __syncthreads();

        f16x8 ah[4], al[4], bh[4], bl[4];
        #pragma unroll
        for (int i = 0; i < 4; i++) {
            int ra = (fm + i * 16 + lm) * 32 + lq * 8;
            ah[i] = *(const f16x8*)(sAh + ra);
            al[i] = *(const f16x8*)(sAl + ra);
            int rb_ = (fn + i * 16 + lm) * 32 + lq * 8;
            bh[i] = *(const f16x8*)(sBh + rb_);
            bl[i] = *(const f16x8*)(sBl + rb_);
        }
        #pragma unroll
        for (int i = 0; i < 4; i++)
            #pragma unroll
            for (int j = 0; j < 4; j++) {
                acc[i][j] = __builtin_amdgcn_mfma_f32_16x16x32_f16(ah[i], bh[j], acc[i][j], 0, 0, 0);
                acc[i][j] = __builtin_amdgcn_mfma_f32_16x16x32_f16(ah[i], bl[j], acc[i][j], 0, 0, 0);
                acc[i][j] = __builtin_amdgcn_mfma_f32_16x16x32_f16(al[i], bh[j], acc[i][j], 0, 0, 0);
            }
        __syncthreads();
    }

    // epilogue: C/D layout col=lane&15, row=quad*4+reg
    #pragma unroll
    for (int j = 0; j < 4; j++) {
        int n = n0 + fn + j * 16 + lm;
        float bb = bias[n];
        #pragma unroll
        for (int i = 0; i < 4; i++) {
            #pragma unroll
            for (int r = 0; r < 4; r++) {
                int m = m0 + fm + i * 16 + lq * 4 + r;
                int gm = m_off_out + m;
                int row = map_out ? tmap_dev(gm) : gm;
                C[(size_t)row * ldc + n] = acc[i][j][r] + bb;
            }
        }
    }
}

__global__ __launch_bounds__(256, 2)
void gemm_f16s(const _Float16* __restrict__ Ah, const _Float16* __restrict__ Al,
               const _Float16* __restrict__ Wh, const _Float16* __restrict__ Wl,
               const float* __restrict__ bias, float* __restrict__ C,
               int ldc, int map_out, int m_off_out)
{
    gemm_core(Ah, Al, Wh, Wl, bias, C, ldc, map_out, m_off_out,
              blockIdx.x * 128, blockIdx.y * 128);
}

__global__ __launch_bounds__(256, 2)
void gemm_f16s_qkv3(const _Float16* __restrict__ Ah, const _Float16* __restrict__ Al,
                    const _Float16* __restrict__ WTh, const _Float16* __restrict__ WTl,
                    const float* __restrict__ bq, const float* __restrict__ bk,
                    const float* __restrict__ bv,
                    float* __restrict__ Q, float* __restrict__ K, float* __restrict__ V)
{
    const _Float16* wh = WTh + (size_t)blockIdx.z * 1048576;
    const _Float16* wl = WTl + (size_t)blockIdx.z * 1048576;
    const float* bias = (blockIdx.z == 0) ? bq : ((blockIdx.z == 1) ? bk : bv);
    float* C = (blockIdx.z == 0) ? Q : ((blockIdx.z == 1) ? K : V);
    gemm_core(Ah, Al, wh, wl, bias, C, 1024, 0, 0, blockIdx.x * 128, blockIdx.y * 128);
}

// ---------------------------------------------------------------------------
// Spatial attention, S=256, chunk-local rows. One block per (frame, head).
// Single pass, no max subtraction (|scores| << 88). Output: split f16 hi/lo.
// grid: (32, 16)
// ---------------------------------------------------------------------------
__global__ __launch_bounds__(256, 2)
void attn_s(const float* __restrict__ Qb, const float* __restrict__ Kb,
            const float* __restrict__ Vb, const float* __restrict__ RB,
            _Float16* __restrict__ Ch, _Float16* __restrict__ Cl)
{
    __shared__ float Kt[64 * 64];
    __shared__ float Vt[64 * 64];
    __shared__ float Bt[512];
    const int tid = threadIdx.x;
    const int frame = blockIdx.x;
    const int head = blockIdx.y;
    const int s = tid;
    const size_t rowbase = (size_t)frame * 256;

    float q[64];
    {
        const float* qp = Qb + (rowbase + s) * 1024 + (size_t)head * 64;
        #pragma unroll
        for (int l = 0; l < 16; l++) {
            float4 t4 = *(const float4*)(qp + (l << 2));
            q[l * 4 + 0] = t4.x; q[l * 4 + 1] = t4.y;
            q[l * 4 + 2] = t4.z; q[l * 4 + 3] = t4.w;
        }
    }
    #pragma unroll
    for (int l = 0; l < 2; l++) {
        int idx = tid + l * 256;
        if (idx < 511) Bt[idx] = RB[(size_t)(256 + idx) * 16 + head];
    }

    float ctx[64];
    #pragma unroll
    for (int d = 0; d < 64; d++) ctx[d] = 0.0f;
    float lsum = 0.0f;

    for (int jt = 0; jt < 4; jt++) {
        __syncthreads();
        #pragma unroll
        for (int l = 0; l < 4; l++) {
            int e = (tid + l * 256) << 2;
            int j = e >> 6, d = e & 63;
            size_t src = (rowbase + jt * 64 + j) * 1024 + (size_t)head * 64 + d;
            *(float4*)&Kt[e] = *(const float4*)(Kb + src);
            *(float4*)&Vt[e] = *(const float4*)(Vb + src);
        }
        __syncthreads();

        const int bofs = jt * 64 - s + 255;
        for (int j = 0; j < 64; j++) {
            const float* kr = Kt + (j << 6);
            float d0 = 0.f, d1 = 0.f, d2 = 0.f, d3 = 0.f;
            #pragma unroll
            for (int d = 0; d < 64; d += 4) {
                d0 = fmaf(q[d + 0], kr[d + 0], d0);
                d1 = fmaf(q[d + 1], kr[d + 1], d1);
                d2 = fmaf(q[d + 2], kr[d + 2], d2);
                d3 = fmaf(q[d + 3], kr[d + 3], d3);
            }
            float sc = ((d0 + d1) + (d2 + d3)) * 0.125f + Bt[bofs + j];
            float p = __expf(sc);
            lsum += p;
            const float* vr = Vt + (j << 6);
            #pragma unroll
            for (int d = 0; d < 64; d += 4) {
                ctx[d + 0] = fmaf(p, vr[d + 0], ctx[d + 0]);
                ctx[d + 1] = fmaf(p, vr[d + 1], ctx[d + 1]);
                ctx[d + 2] = fmaf(p, vr[d + 2], ctx[d + 2]);
                ctx[d + 3] = fmaf(p, vr[d + 3], ctx[d + 3]);
            }
        }
    }

    float inv = 1.0f / lsum;
    size_t ob = (rowbase + s) * 1024 + (size_t)head * 64;
    #pragma unroll
    for (int d0 = 0; d0 < 64; d0 += 8) {
        f16x8 vh, vl;
        #pragma unroll
        for (int r = 0; r < 8; r++) {
            float v = ctx[d0 + r] * inv;
            _Float16 h = (_Float16)v;
            vh[r] = h;
            vl[r] = (_Float16)(v - (float)h);
        }
        *(f16x8*)(Ch + ob + d0) = vh;
        *(f16x8*)(Cl + ob + d0) = vl;
    }
}

// ---------------------------------------------------------------------------
// Temporal attention, S=32, chunk-local. 256 thr = 8 heads x 32 rows.
// grid: (256, 2). Output split f16 hi/lo.
// ---------------------------------------------------------------------------
__global__ __launch_bounds__(256, 2)
void attn_t(const float* __restrict__ Qb, const float* __restrict__ Kb,
            const float* __restrict__ Vb, const float* __restrict__ RB,
            _Float16* __restrict__ Ch, _Float16* __restrict__ Cl)
{
    const int tid = threadIdx.x;
    const int bx = blockIdx.x;
    const int head = blockIdx.y * 8 + (tid >> 5);
    const int s = tid & 31;
    const size_t rowbase = (size_t)bx * 32;

    float q[64];
    {
        const float* qp = Qb + (rowbase + s) * 1024 + (size_t)head * 64;
        #pragma unroll
        for (int l = 0; l < 16; l++) {
            float4 t4 = *(const float4*)(qp + (l << 2));
            q[l * 4 + 0] = t4.x; q[l * 4 + 1] = t4.y;
            q[l * 4 + 2] = t4.z; q[l * 4 + 3] = t4.w;
        }
    }

    float ctx[64];
    #pragma unroll
    for (int d = 0; d < 64; d++) ctx[d] = 0.0f;
    float lsum = 0.0f;
    const float* kbase = Kb + rowbase * 1024 + (size_t)head * 64;
    const float* vbase = Vb + rowbase * 1024 + (size_t)head * 64;
    const float* rbp = RB + (size_t)(511 - s) * 16 + head;

    for (int j = 0; j < 32; j++) {
        const float* kr = kbase + (size_t)j * 1024;
        float d0 = 0.f, d1 = 0.f, d2 = 0.f, d3 = 0.f;
        #pragma unroll
        for (int d = 0; d < 64; d += 4) {
            float4 k4 = *(const float4*)(kr + d);
            d0 = fmaf(q[d + 0], k4.x, d0);
            d1 = fmaf(q[d + 1], k4.y, d1);
            d2 = fmaf(q[d + 2], k4.z, d2);
            d3 = fmaf(q[d + 3], k4.w, d3);
        }
        float sc = ((d0 + d1) + (d2 + d3)) * 0.125f + rbp[(size_t)j * 16];
        float p = __expf(sc);
        lsum += p;
        const float* vr = vbase + (size_t)j * 1024;
        #pragma unroll
        for (int d = 0; d < 64; d += 4) {
            float4 v4 = *(const float4*)(vr + d);
            ctx[d + 0] = fmaf(p, v4.x, ctx[d + 0]);
            ctx[d + 1] = fmaf(p, v4.y, ctx[d + 1]);
            ctx[d + 2] = fmaf(p, v4.z, ctx[d + 2]);
            ctx[d + 3] = fmaf(p, v4.w, ctx[d + 3]);
        }
    }

    float inv = 1.0f / lsum;
    size_t ob = (rowbase + s) * 1024 + (size_t)head * 64;
    #pragma unroll
    for (int d0 = 0; d0 < 64; d0 += 8) {
        f16x8 vh, vl;
        #pragma unroll
        for (int r = 0; r < 8; r++) {
            float v = ctx[d0 + r] * inv;
            _Float16 h = (_Float16)v;
            vh[r] = h;
            vl[r] = (_Float16)(v - (float)h);
        }
        *(f16x8*)(Ch + ob + d0) = vh;
        *(f16x8*)(Cl + ob + d0) = vl;
    }
}

// ---------------------------------------------------------------------------
// Token selection (fp32, unchanged)
// ---------------------------------------------------------------------------
__global__ __launch_bounds__(256)
void colsum_part_kernel(const float* __restrict__ SC, float* __restrict__ P)
{
    int bid = blockIdx.x;
    int b = bid >> 7, chunk = bid & 127;
    int base = b * 8192 + chunk * 64;
    int k = threadIdx.x;
    float sum = 0.0f;
    for (int r = 0; r < 64; r++)
        sum += __expf(SC[(size_t)(base + r) * 256 + k]);
    P[(size_t)bid * 256 + k] = sum;
}

__global__ __launch_bounds__(256)
void colsum_reduce_kernel(const float* __restrict__ P, float* __restrict__ CS)
{
    int b = blockIdx.x;
    int k = threadIdx.x;
    float s = 0.0f;
    for (int c = 0; c < 128; c++)
        s += P[(size_t)(b * 128 + c) * 256 + k];
    CS[b * 256 + k] = s;
}

__global__ __launch_bounds__(256)
void wts_kernel(float* __restrict__ SC, const float* __restrict__ CS)
{
    int i4 = blockIdx.x * 256 + threadIdx.x;
    int e  = i4 << 2;
    int b  = e >> 21;
    int k  = e & 255;
    const float* cs = CS + b * 256 + k;
    float4 v = *(float4*)(SC + e);
    v.x = __expf(v.x) / cs[0];
    v.y = __expf(v.y) / cs[1];
    v.z = __expf(v.z) / cs[2];
    v.w = __expf(v.w) / cs[3];
    *(float4*)(SC + e) = v;
}

__global__ __launch_bounds__(256)
void gemm_sel(const float* __restrict__ W, const float* __restrict__ F,
              float* __restrict__ SEL)
{
    __shared__ float As[32][33];
    __shared__ float Bs[32][64];
    const int tid = threadIdx.x;
    const int n0 = blockIdx.x * 64;
    const int m2 = blockIdx.y * 32;
    const int b   = m2 >> 8;
    const int k0_ = m2 & 255;
    const float* Wb = W + (size_t)b * (8192 * 256);
    const float* Fb = F + (size_t)b * (8192 * 1024);
    const int tx = tid & 15, ty = tid >> 4;

    float acc[2][4];
    #pragma unroll
    for (int i = 0; i < 2; i++)
        #pragma unroll
        for (int j = 0; j < 4; j++) acc[i][j] = 0.0f;

    const int akk = tid >> 3, amm = (tid & 7) << 2;
    const int bkk = tid >> 4, bnn = (tid & 15) << 2;

    for (int kc = 0; kc < 8192; kc += 32) {
        float4 av  = *(const float4*)(Wb + (size_t)(kc + akk) * 256 + k0_ + amm);
        float4 bv0 = *(const float4*)(Fb + (size_t)(kc + bkk) * 1024 + n0 + bnn);
        float4 bv1 = *(const float4*)(Fb + (size_t)(kc + bkk + 16) * 1024 + n0 + bnn);
        As[akk][amm + 0] = av.x; As[akk][amm + 1] = av.y;
        As[akk][amm + 2] = av.z; As[akk][amm + 3] = av.w;
        *(float4*)&Bs[bkk][bnn]      = bv0;
        *(float4*)&Bs[bkk + 16][bnn] = bv1;
        __syncthreads();
        #pragma unroll
        for (int kk = 0; kk < 32; kk++) {
            float a0 = As[kk][ty * 2 + 0];
            float a1 = As[kk][ty * 2 + 1];
            float b0 = Bs[kk][tx * 4 + 0];
            float b1 = Bs[kk][tx * 4 + 1];
            float b2 = Bs[kk][tx * 4 + 2];
            float b3 = Bs[kk][tx * 4 + 3];
            acc[0][0] = fmaf(a0, b0, acc[0][0]);
            acc[0][1] = fmaf(a0, b1, acc[0][1]);
            acc[0][2] = fmaf(a0, b2, acc[0][2]);
            acc[0][3] = fmaf(a0, b3, acc[0][3]);
            acc[1][0] = fmaf(a1, b0, acc[1][0]);
            acc[1][1] = fmaf(a1, b1, acc[1][1]);
            acc[1][2] = fmaf(a1, b2, acc[1][2]);
            acc[1][3] = fmaf(a1, b3, acc[1][3]);
        }
        __syncthreads();
    }
    #pragma unroll
    for (int i = 0; i < 2; i++) {
        float* op = SEL + (size_t)(m2 + ty * 2 + i) * 1024 + n0 + tx * 4;
        float4 o = { acc[i][0], acc[i][1], acc[i][2], acc[i][3] };
        *(float4*)op = o;
    }
}

__global__ __launch_bounds__(256)
void pool_kernel(const float* __restrict__ SEL, float* __restrict__ out)
{
    int i4 = blockIdx.x * 256 + threadIdx.x;
    int e  = i4 << 2;
    int row = e >> 10;
    int b = row / 448;
    int r = row - b * 448;
    int c = e & 1023;
    const float* sb = SEL + (size_t)b * (256 * 1024);
    float4 o;
    if (r < 256) {
        o = *(const float4*)(sb + (size_t)r * 1024 + c);
    } else if (r < 384) {
        int r2 = (r - 256) * 2;
        float4 x0 = *(const float4*)(sb + (size_t)r2 * 1024 + c);
        float4 x1 = *(const float4*)(sb + (size_t)(r2 + 1) * 1024 + c);
        o.x = 0.5f * (x0.x + x1.x); o.y = 0.5f * (x0.y + x1.y);
        o.z = 0.5f * (x0.z + x1.z); o.w = 0.5f * (x0.w + x1.w);
    } else {
        int r4 = (r - 384) * 4;
        float4 x0 = *(const float4*)(sb + (size_t)(r4 + 0) * 1024 + c);
        float4 x1 = *(const float4*)(sb + (size_t)(r4 + 1) * 1024 + c);
        float4 x2 = *(const float4*)(sb + (size_t)(r4 + 2) * 1024 + c);
        float4 x3 = *(const float4*)(sb + (size_t)(r4 + 3) * 1024 + c);
        o.x = 0.25f * (x0.x + x1.x + x2.x + x3.x);
        o.y = 0.25f * (x0.y + x1.y + x2.y + x3.y);
        o.z = 0.25f * (x0.z + x1.z + x2.z + x3.z);
        o.w = 0.25f * (x0.w + x1.w + x2.w + x3.w);
    }
    *(float4*)(out + e) = o;
}

// ---------------------------------------------------------------------------
extern "C" void kernel_launch(void* const* d_in, const int* in_sizes, int n_in,
                              void* d_out, int out_size, void* d_ws, size_t ws_size,
                              hipStream_t stream)
{
    const float* x    = (const float*)d_in[0];
    const float* wq   = (const float*)d_in[1];
    const float* bq   = (const float*)d_in[2];
    const float* wk   = (const float*)d_in[3];
    const float* bk   = (const float*)d_in[4];
    const float* wv   = (const float*)d_in[5];
    const float* bv   = (const float*)d_in[6];
    const float* wd   = (const float*)d_in[7];
    const float* bd   = (const float*)d_in[8];
    const float* rb   = (const float*)d_in[9];
    const float* selw = (const float*)d_in[10];
    const float* selb = (const float*)d_in[11];
    float* out = (float*)d_out;

    // workspace layout, total 240 MB (ws >= 256 MB verified in round 3):
    float* H = (float*)d_ws;                 // 16M floats (64 MB)
    float* Q = H + 16777216;                 // 8M floats (32 MB, chunk)
    float* K = Q + 8388608;                  // 32 MB
    float* V = K + 8388608;                  // 32 MB
    _Float16* Ah  = (_Float16*)(V + 8388608);   // 8M f16 (16 MB, chunk)
    _Float16* Al  = Ah + 8388608;
    _Float16* CXh = Al + 8388608;
    _Float16* CXl = CXh + 8388608;
    _Float16* WTh = CXl + 8388608;           // 4 x 1M f16 (8 MB)
    _Float16* WTl = WTh + 4194304;           // 8 MB
    // selection aliases (after all attention stages):
    float* SC   = Q;                          // [16384][256] fp32 (16 MB)
    float* SEL  = K;                          // [2][256][1024]
    float* PART = K + 524288;
    float* CSUM = PART + 65536;

    const dim3 blk(256);

    for (int a = 0; a < 4; a++) {
        const float* hin = (a == 0) ? x : H;
        const int mi = (a & 1);
        const size_t wo = (size_t)a * 1048576;
        const int bo = a * 1024;
        const float* rba = rb + (size_t)a * 1023 * 16;

        conv_wT<<<dim3(16, 16), blk, 0, stream>>>(wq + wo, WTh,           WTl,           1024);
        conv_wT<<<dim3(16, 16), blk, 0, stream>>>(wk + wo, WTh + 1048576, WTl + 1048576, 1024);
        conv_wT<<<dim3(16, 16), blk, 0, stream>>>(wv + wo, WTh + 2097152, WTl + 2097152, 1024);
        conv_wT<<<dim3(16, 16), blk, 0, stream>>>(wd + wo, WTh + 3145728, WTl + 3145728, 1024);

        for (int c = 0; c < 2; c++) {
            const int mo = c * 8192;
            conv_act<<<4096, blk, 0, stream>>>(hin, Ah, Al, mi, mo);
            gemm_f16s_qkv3<<<dim3(8, 64, 3), blk, 0, stream>>>(
                Ah, Al, WTh, WTl, bq + bo, bk + bo, bv + bo, Q, K, V);
            if (mi == 0)
                attn_s<<<dim3(32, 16), blk, 0, stream>>>(Q, K, V, rba, CXh, CXl);
            else
                attn_t<<<dim3(256, 2), blk, 0, stream>>>(Q, K, V, rba, CXh, CXl);
            gemm_f16s<<<dim3(8, 64), blk, 0, stream>>>(
                CXh, CXl, WTh + 3145728, WTl + 3145728, bd + bo, H, 1024, mi, mo);
        }
    }

    // token selection
    conv_wT<<<dim3(4, 16), blk, 0, stream>>>(selw, WTh, WTl, 256);
    for (int c = 0; c < 2; c++) {
        conv_act<<<4096, blk, 0, stream>>>(H, Ah, Al, 0, c * 8192);
        gemm_f16s<<<dim3(2, 64), blk, 0, stream>>>(
            Ah, Al, WTh, WTl, selb, SC, 256, 0, c * 8192);
    }
    colsum_part_kernel<<<256, blk, 0, stream>>>(SC, PART);
    colsum_reduce_kernel<<<2, blk, 0, stream>>>(PART, CSUM);
    wts_kernel<<<4096, blk, 0, stream>>>(SC, CSUM);
    gemm_sel<<<dim3(16, 16), blk, 0, stream>>>(SC, H, SEL);
    pool_kernel<<<896, blk, 0, stream>>>(SEL, out);
}

// Round 5
// 3471.342 us; speedup vs baseline: 3.5148x; 1.0731x over previous
//
#include <hip/hip_runtime.h>
#include <stdint.h>

// B=2, T=32, N=256, E=1024, H=16, D=64, L=2, K=256, MAXLEN=512
// tokens = 16384, GEMMs chunked in 2 x 8192 rows.

using f16x8 = __attribute__((ext_vector_type(8))) _Float16;
using f16x4 = __attribute__((ext_vector_type(4))) _Float16;
using f32x4 = __attribute__((ext_vector_type(4))) float;

__device__ __forceinline__ int tmap_dev(int m) {
    // temporal token m = (b*N+n)*T + t  ->  flat row (b*T+t)*N + n
    int bx = m >> 5;
    int s  = m & 31;
    int b  = bx >> 8;
    int n  = bx & 255;
    return (((b << 5) + s) << 8) + n;
}

__device__ __forceinline__ void load16(const _Float16* g, _Float16* l)
{
    __builtin_amdgcn_global_load_lds(
        (const __attribute__((address_space(1))) unsigned int*)g,
        (__attribute__((address_space(3))) unsigned int*)l,
        16, 0, 0);
}

// ---------------------------------------------------------------------------
// x fp32 -> split f16 hi/lo (a=0 only, identity map). chunk-local dst.
// ---------------------------------------------------------------------------
__global__ __launch_bounds__(256)
void conv_act(const float* __restrict__ src, _Float16* __restrict__ dh,
              _Float16* __restrict__ dl, int m_off)
{
    int idx = blockIdx.x * 256 + threadIdx.x;
    int e = idx << 3;
    int ml = e >> 10, col = e & 1023;
    const float* s = src + (size_t)(m_off + ml) * 1024 + col;
    float4 a = *(const float4*)s;
    float4 b = *(const float4*)(s + 4);
    float vv[8] = {a.x, a.y, a.z, a.w, b.x, b.y, b.z, b.w};
    f16x8 vh, vl;
    #pragma unroll
    for (int r = 0; r < 8; r++) {
        _Float16 h = (_Float16)vv[r];
        vh[r] = h;
        vl[r] = (_Float16)(vv[r] - (float)h);
    }
    *(f16x8*)(dh + (size_t)ml * 1024 + col) = vh;
    *(f16x8*)(dl + (size_t)ml * 1024 + col) = vl;
}

// ---------------------------------------------------------------------------
// Weight fp32 [1024][ncols] -> transposed split f16 [ncols][1024].
// ---------------------------------------------------------------------------
__global__ __launch_bounds__(256)
void conv_wT(const float* __restrict__ W, _Float16* __restrict__ Th,
             _Float16* __restrict__ Tl, int ncols)
{
    __shared__ float Ls[64][65];
    const int n0 = blockIdx.x * 64, k0 = blockIdx.y * 64;
    const int t = threadIdx.x;
    const int kk = t >> 4, nn = (t & 15) << 2;
    #pragma unroll
    for (int i = 0; i < 4; i++) {
        float4 v = *(const float4*)(W + (size_t)(k0 + kk + 16 * i) * ncols + n0 + nn);
        Ls[kk + 16 * i][nn + 0] = v.x; Ls[kk + 16 * i][nn + 1] = v.y;
        Ls[kk + 16 * i][nn + 2] = v.z; Ls[kk + 16 * i][nn + 3] = v.w;
    }
    __syncthreads();
    const int nl = t >> 4, kc = (t & 15) << 2;
    #pragma unroll
    for (int i = 0; i < 4; i++) {
        int n = nl + 16 * i;
        f16x4 hh, ll;
        #pragma unroll
        for (int c = 0; c < 4; c++) {
            float v = Ls[kc + c][n];
            _Float16 h = (_Float16)v;
            hh[c] = h;
            ll[c] = (_Float16)(v - (float)h);
        }
        *(f16x4*)(Th + (size_t)(n0 + n) * 1024 + k0 + kc) = hh;
        *(f16x4*)(Tl + (size_t)(n0 + n) * 1024 + k0 + kc) = ll;
    }
}

// ---------------------------------------------------------------------------
// Split-f16 MFMA GEMM core, tile 128x128, BK=32, K=1024, lda/ldb=1024.
// Gather map on A-input rows; EPI 0: fp32 C (scatter map), EPI 1: split-f16 pair.
// ---------------------------------------------------------------------------
template<int EPI>
__device__ __forceinline__ void gemm_core(
    const _Float16* __restrict__ Ah, const _Float16* __restrict__ Al,
    const _Float16* __restrict__ Wh, const _Float16* __restrict__ Wl,
    const float* __restrict__ bias,
    float* __restrict__ C, _Float16* __restrict__ Ch, _Float16* __restrict__ Cl,
    int ldc, int map_in, int m_off_in, int map_out, int m_off_out,
    int n0, int m0)
{
    __shared__ _Float16 sAh[4096], sAl[4096], sBh[4096], sBl[4096];
    const int tid = threadIdx.x;
    const int lane = tid & 63;
    const int wv = tid >> 6;
    const int fm = (wv >> 1) << 6;
    const int fn = (wv & 1) << 6;
    const int lm = lane & 15, lq = lane >> 4;

    f32x4 acc[4][4] = {};

    const int srow = tid >> 2;
    const int skc  = (tid & 3) << 3;
    const int gm0 = m_off_in + m0 + srow;
    const int gm1 = gm0 + 64;
    const int r0 = map_in ? tmap_dev(gm0) : gm0;
    const int r1 = map_in ? tmap_dev(gm1) : gm1;
    const _Float16* gAh0 = Ah + (size_t)r0 * 1024 + skc;
    const _Float16* gAh1 = Ah + (size_t)r1 * 1024 + skc;
    const _Float16* gAl0 = Al + (size_t)r0 * 1024 + skc;
    const _Float16* gAl1 = Al + (size_t)r1 * 1024 + skc;
    const _Float16* gB0 = Wh + (size_t)(n0 + srow) * 1024 + skc;
    const _Float16* gB1 = Wl + (size_t)(n0 + srow) * 1024 + skc;
    const int lo = tid << 3;

    for (int k0 = 0; k0 < 1024; k0 += 32) {
        load16(gAh0 + k0, sAh + lo);
        load16(gAh1 + k0, sAh + lo + 2048);
        load16(gAl0 + k0, sAl + lo);
        load16(gAl1 + k0, sAl + lo + 2048);
        load16(gB0 + k0,         sBh + lo);
        load16(gB0 + k0 + 65536, sBh + lo + 2048);
        load16(gB1 + k0,         sBl + lo);
        load16(gB1 + k0 + 65536, sBl + lo + 2048);
        __syncthreads();

        f16x8 ah[4], al[4], bh[4], bl[4];
        #pragma unroll
        for (int i = 0; i < 4; i++) {
            int ra = (fm + i * 16 + lm) * 32 + lq * 8;
            ah[i] = *(const f16x8*)(sAh + ra);
            al[i] = *(const f16x8*)(sAl + ra);
            int rb_ = (fn + i * 16 + lm) * 32 + lq * 8;
            bh[i] = *(const f16x8*)(sBh + rb_);
            bl[i] = *(const f16x8*)(sBl + rb_);
        }
        #pragma unroll
        for (int i = 0; i < 4; i++)
            #pragma unroll
            for (int j = 0; j < 4; j++) {
                acc[i][j] = __builtin_amdgcn_mfma_f32_16x16x32_f16(ah[i], bh[j], acc[i][j], 0, 0, 0);
                acc[i][j] = __builtin_amdgcn_mfma_f32_16x16x32_f16(ah[i], bl[j], acc[i][j], 0, 0, 0);
                acc[i][j] = __builtin_amdgcn_mfma_f32_16x16x32_f16(al[i], bh[j], acc[i][j], 0, 0, 0);
            }
        __syncthreads();
    }

    #pragma unroll
    for (int j = 0; j < 4; j++) {
        int n = n0 + fn + j * 16 + lm;
        float bb = bias[n];
        #pragma unroll
        for (int i = 0; i < 4; i++) {
            #pragma unroll
            for (int r = 0; r < 4; r++) {
                int gm = m_off_out + m0 + fm + i * 16 + lq * 4 + r;
                int row = map_out ? tmap_dev(gm) : gm;
                float v = acc[i][j][r] + bb;
                if (EPI == 0) {
                    C[(size_t)row * ldc + n] = v;
                } else {
                    _Float16 h = (_Float16)v;
                    Ch[(size_t)row * 1024 + n] = h;
                    Cl[(size_t)row * 1024 + n] = (_Float16)(v - (float)h);
                }
            }
        }
    }
}

__global__ __launch_bounds__(256, 2)
void gemm_f16s_f32(const _Float16* __restrict__ Ah, const _Float16* __restrict__ Al,
                   int map_in, int m_off_in,
                   const _Float16* __restrict__ Wh, const _Float16* __restrict__ Wl,
                   const float* __restrict__ bias, float* __restrict__ C, int ldc,
                   int map_out, int m_off_out)
{
    gemm_core<0>(Ah, Al, Wh, Wl, bias, C, nullptr, nullptr, ldc,
                 map_in, m_off_in, map_out, m_off_out,
                 blockIdx.x * 128, blockIdx.y * 128);
}

__global__ __launch_bounds__(256, 2)
void gemm_f16s_h(const _Float16* __restrict__ Ah, const _Float16* __restrict__ Al,
                 int map_in, int m_off_in,
                 const _Float16* __restrict__ Wh, const _Float16* __restrict__ Wl,
                 const float* __restrict__ bias,
                 _Float16* __restrict__ Ch, _Float16* __restrict__ Cl,
                 int map_out, int m_off_out)
{
    gemm_core<1>(Ah, Al, Wh, Wl, bias, nullptr, Ch, Cl, 1024,
                 map_in, m_off_in, map_out, m_off_out,
                 blockIdx.x * 128, blockIdx.y * 128);
}

__global__ __launch_bounds__(256, 2)
void gemm_f16s_qkv3(const _Float16* __restrict__ Ah, const _Float16* __restrict__ Al,
                    int map_in, int m_off_in,
                    const _Float16* __restrict__ WTh, const _Float16* __restrict__ WTl,
                    const float* __restrict__ bq, const float* __restrict__ bk,
                    const float* __restrict__ bv,
                    float* __restrict__ Q, float* __restrict__ K, float* __restrict__ V)
{
    const _Float16* wh = WTh + (size_t)blockIdx.z * 1048576;
    const _Float16* wl = WTl + (size_t)blockIdx.z * 1048576;
    const float* bias = (blockIdx.z == 0) ? bq : ((blockIdx.z == 1) ? bk : bv);
    float* C = (blockIdx.z == 0) ? Q : ((blockIdx.z == 1) ? K : V);
    gemm_core<0>(Ah, Al, wh, wl, bias, C, nullptr, nullptr, 1024,
                 map_in, m_off_in, 0, 0, blockIdx.x * 128, blockIdx.y * 128);
}

// ---------------------------------------------------------------------------
// Spatial attention, S=256, 128 threads = half frame x 1 head.
// Single pass, no max subtraction (|scores| << 88). grid: (64, 16) per chunk.
// ---------------------------------------------------------------------------
__global__ __launch_bounds__(128, 2)
void attn_s(const float* __restrict__ Qb, const float* __restrict__ Kb,
            const float* __restrict__ Vb, const float* __restrict__ RB,
            _Float16* __restrict__ Ch, _Float16* __restrict__ Cl)
{
    __shared__ float Kt[4096];
    __shared__ float Vt[4096];
    __shared__ float Bt[512];
    const int tid = threadIdx.x;
    const int frame = blockIdx.x >> 1;
    const int half  = blockIdx.x & 1;
    const int head = blockIdx.y;
    const int s = half * 128 + tid;
    const size_t rowbase = (size_t)frame * 256;

    float q[64];
    {
        const float* qp = Qb + (rowbase + s) * 1024 + (size_t)head * 64;
        #pragma unroll
        for (int l = 0; l < 16; l++) {
            float4 t4 = *(const float4*)(qp + (l << 2));
            q[l * 4 + 0] = t4.x; q[l * 4 + 1] = t4.y;
            q[l * 4 + 2] = t4.z; q[l * 4 + 3] = t4.w;
        }
    }
    #pragma unroll
    for (int l = 0; l < 4; l++) {
        int idx = tid + l * 128;
        if (idx < 511) Bt[idx] = RB[(size_t)(256 + idx) * 16 + head];
    }

    float ctx[64];
    #pragma unroll
    for (int d = 0; d < 64; d++) ctx[d] = 0.0f;
    float lsum = 0.0f;

    for (int jt = 0; jt < 4; jt++) {
        __syncthreads();
        #pragma unroll
        for (int l = 0; l < 8; l++) {
            int idx = tid + l * 128;
            int e = idx << 2;
            int j = e >> 6, d = e & 63;
            size_t src = (rowbase + jt * 64 + j) * 1024 + (size_t)head * 64 + d;
            *(float4*)&Kt[e] = *(const float4*)(Kb + src);
            *(float4*)&Vt[e] = *(const float4*)(Vb + src);
        }
        __syncthreads();

        const int bofs = jt * 64 - s + 255;
        for (int j = 0; j < 64; j++) {
            const float* kr = Kt + (j << 6);
            float d0 = 0.f, d1 = 0.f, d2 = 0.f, d3 = 0.f;
            #pragma unroll
            for (int d = 0; d < 64; d += 4) {
                d0 = fmaf(q[d + 0], kr[d + 0], d0);
                d1 = fmaf(q[d + 1], kr[d + 1], d1);
                d2 = fmaf(q[d + 2], kr[d + 2], d2);
                d3 = fmaf(q[d + 3], kr[d + 3], d3);
            }
            float sc = ((d0 + d1) + (d2 + d3)) * 0.125f + Bt[bofs + j];
            float p = __expf(sc);
            lsum += p;
            const float* vr = Vt + (j << 6);
            #pragma unroll
            for (int d = 0; d < 64; d += 4) {
                ctx[d + 0] = fmaf(p, vr[d + 0], ctx[d + 0]);
                ctx[d + 1] = fmaf(p, vr[d + 1], ctx[d + 1]);
                ctx[d + 2] = fmaf(p, vr[d + 2], ctx[d + 2]);
                ctx[d + 3] = fmaf(p, vr[d + 3], ctx[d + 3]);
            }
        }
    }

    float inv = 1.0f / lsum;
    size_t ob = (rowbase + s) * 1024 + (size_t)head * 64;
    #pragma unroll
    for (int d0 = 0; d0 < 64; d0 += 8) {
        f16x8 vh, vl;
        #pragma unroll
        for (int r = 0; r < 8; r++) {
            float v = ctx[d0 + r] * inv;
            _Float16 h = (_Float16)v;
            vh[r] = h;
            vl[r] = (_Float16)(v - (float)h);
        }
        *(f16x8*)(Ch + ob + d0) = vh;
        *(f16x8*)(Cl + ob + d0) = vl;
    }
}

// ---------------------------------------------------------------------------
// Temporal attention, S=32, 128 threads = 4 heads x 32 rows. grid (256, 4).
// ---------------------------------------------------------------------------
__global__ __launch_bounds__(128, 2)
void attn_t(const float* __restrict__ Qb, const float* __restrict__ Kb,
            const float* __restrict__ Vb, const float* __restrict__ RB,
            _Float16* __restrict__ Ch, _Float16* __restrict__ Cl)
{
    const int tid = threadIdx.x;
    const int head = blockIdx.y * 4 + (tid >> 5);
    const int s = tid & 31;
    const size_t rowbase = (size_t)blockIdx.x * 32;

    float q[64];
    {
        const float* qp = Qb + (rowbase + s) * 1024 + (size_t)head * 64;
        #pragma unroll
        for (int l = 0; l < 16; l++) {
            float4 t4 = *(const float4*)(qp + (l << 2));
            q[l * 4 + 0] = t4.x; q[l * 4 + 1] = t4.y;
            q[l * 4 + 2] = t4.z; q[l * 4 + 3] = t4.w;
        }
    }

    float ctx[64];
    #pragma unroll
    for (int d = 0; d < 64; d++) ctx[d] = 0.0f;
    float lsum = 0.0f;
    const float* kbase = Kb + rowbase * 1024 + (size_t)head * 64;
    const float* vbase = Vb + rowbase * 1024 + (size_t)head * 64;
    const float* rbp = RB + (size_t)(511 - s) * 16 + head;

    for (int j = 0; j < 32; j++) {
        const float* kr = kbase + (size_t)j * 1024;
        float d0 = 0.f, d1 = 0.f, d2 = 0.f, d3 = 0.f;
        #pragma unroll
        for (int d = 0; d < 64; d += 4) {
            float4 k4 = *(const float4*)(kr + d);
            d0 = fmaf(q[d + 0], k4.x, d0);
            d1 = fmaf(q[d + 1], k4.y, d1);
            d2 = fmaf(q[d + 2], k4.z, d2);
            d3 = fmaf(q[d + 3], k4.w, d3);
        }
        float sc = ((d0 + d1) + (d2 + d3)) * 0.125f + rbp[(size_t)j * 16];
        float p = __expf(sc);
        lsum += p;
        const float* vr = vbase + (size_t)j * 1024;
        #pragma unroll
        for (int d = 0; d < 64; d += 4) {
            float4 v4 = *(const float4*)(vr + d);
            ctx[d + 0] = fmaf(p, v4.x, ctx[d + 0]);
            ctx[d + 1] = fmaf(p, v4.y, ctx[d + 1]);
            ctx[d + 2] = fmaf(p, v4.z, ctx[d + 2]);
            ctx[d + 3] = fmaf(p, v4.w, ctx[d + 3]);
        }
    }

    float inv = 1.0f / lsum;
    size_t ob = (rowbase + s) * 1024 + (size_t)head * 64;
    #pragma unroll
    for (int d0 = 0; d0 < 64; d0 += 8) {
        f16x8 vh, vl;
        #pragma unroll
        for (int r = 0; r < 8; r++) {
            float v = ctx[d0 + r] * inv;
            _Float16 h = (_Float16)v;
            vh[r] = h;
            vl[r] = (_Float16)(v - (float)h);
        }
        *(f16x8*)(Ch + ob + d0) = vh;
        *(f16x8*)(Cl + ob + d0) = vl;
    }
}

// ---------------------------------------------------------------------------
// Token selection
// ---------------------------------------------------------------------------
__global__ __launch_bounds__(256)
void colsum_part_kernel(const float* __restrict__ SC, float* __restrict__ P)
{
    int bid = blockIdx.x;
    int b = bid >> 7, chunk = bid & 127;
    int base = b * 8192 + chunk * 64;
    int k = threadIdx.x;
    float sum = 0.0f;
    for (int r = 0; r < 64; r++)
        sum += __expf(SC[(size_t)(base + r) * 256 + k]);
    P[(size_t)bid * 256 + k] = sum;
}

__global__ __launch_bounds__(256)
void colsum_reduce_kernel(const float* __restrict__ P, float* __restrict__ CS)
{
    int b = blockIdx.x;
    int k = threadIdx.x;
    float s = 0.0f;
    for (int c = 0; c < 128; c++)
        s += P[(size_t)(b * 128 + c) * 256 + k];
    CS[b * 256 + k] = s;
}

// fused: WTT[b][k][m] = exp(SC[b*8192+m][k]) / CS[b][k], split f16, transposed
__global__ __launch_bounds__(256)
void trans_wts(const float* __restrict__ SC, const float* __restrict__ CS,
               _Float16* __restrict__ Th, _Float16* __restrict__ Tl)
{
    __shared__ float L[64][65];
    const int mt = blockIdx.x * 64;
    const int kt = blockIdx.y * 64;
    const int b  = mt >> 13;
    const int ml = mt & 8191;
    const int tid = threadIdx.x;
    #pragma unroll
    for (int l = 0; l < 4; l++) {
        int idx = tid + 256 * l;
        int r = idx >> 4, c4 = (idx & 15) << 2;
        float4 v = *(const float4*)(SC + (size_t)(mt + r) * 256 + kt + c4);
        L[r][c4 + 0] = __expf(v.x); L[r][c4 + 1] = __expf(v.y);
        L[r][c4 + 2] = __expf(v.z); L[r][c4 + 3] = __expf(v.w);
    }
    __syncthreads();
    #pragma unroll
    for (int l = 0; l < 4; l++) {
        int idx = tid + 256 * l;
        int rk = idx >> 4, c4 = (idx & 15) << 2;
        float inv = 1.0f / CS[b * 256 + kt + rk];
        f16x4 hh, ll;
        #pragma unroll
        for (int u = 0; u < 4; u++) {
            float v = L[c4 + u][rk] * inv;
            _Float16 h = (_Float16)v;
            hh[u] = h;
            ll[u] = (_Float16)(v - (float)h);
        }
        size_t o = ((size_t)b * 256 + kt + rk) * 8192 + ml + c4;
        *(f16x4*)(Th + o) = hh;
        *(f16x4*)(Tl + o) = ll;
    }
}

// H split-f16 [16384][1024] -> transposed [1024][16384] (hi and lo via z)
__global__ __launch_bounds__(256)
void trans_f16(const _Float16* __restrict__ Sh, const _Float16* __restrict__ Sl,
               _Float16* __restrict__ Th, _Float16* __restrict__ Tl)
{
    __shared__ _Float16 L[64][72];
    const int mt = blockIdx.x * 64, et = blockIdx.y * 64;
    const _Float16* S = blockIdx.z ? Sl : Sh;
    _Float16* T = blockIdx.z ? Tl : Th;
    const int tid = threadIdx.x;
    #pragma unroll
    for (int l = 0; l < 2; l++) {
        int v = tid * 2 + l;
        int r = v >> 3, c8 = (v & 7) << 3;
        *(f16x8*)&L[r][c8] = *(const f16x8*)(S + (size_t)(mt + r) * 1024 + et + c8);
    }
    __syncthreads();
    #pragma unroll
    for (int l = 0; l < 2; l++) {
        int v = tid * 2 + l;
        int r = v >> 3, c8 = (v & 7) << 3;
        f16x8 o;
        #pragma unroll
        for (int u = 0; u < 8; u++) o[u] = L[c8 + u][r];
        *(f16x8*)(T + (size_t)(et + r) * 16384 + mt + c8) = o;
    }
}

// SEL partial GEMM: P[z][k][e] = sum_{m in split} WTT[b][k][m] * HT[e][b*8192+m]
// z = b*8+split. grid (8, 2, 16), 256 threads, tile 128x128, K-slice 1024.
__global__ __launch_bounds__(256, 2)
void gemm_selm(const _Float16* __restrict__ Wth, const _Float16* __restrict__ Wtl,
               const _Float16* __restrict__ Hth, const _Float16* __restrict__ Htl,
               float* __restrict__ P)
{
    __shared__ _Float16 sAh[4096], sAl[4096], sBh[4096], sBl[4096];
    const int tid = threadIdx.x;
    const int lane = tid & 63;
    const int wv = tid >> 6;
    const int fm = (wv >> 1) << 6;
    const int fn = (wv & 1) << 6;
    const int lm = lane & 15, lq = lane >> 4;
    const int n0 = blockIdx.x * 128;       // e
    const int m0 = blockIdx.y * 128;       // k_sel
    const int z  = blockIdx.z;
    const int b = z >> 3, sp = z & 7;

    f32x4 acc[4][4] = {};

    const int srow = tid >> 2;
    const int skc  = (tid & 3) << 3;
    const _Float16* gAh0 = Wth + ((size_t)b * 256 + m0 + srow) * 8192 + sp * 1024 + skc;
    const _Float16* gAl0 = Wtl + ((size_t)b * 256 + m0 + srow) * 8192 + sp * 1024 + skc;
    const _Float16* gB0 = Hth + (size_t)(n0 + srow) * 16384 + b * 8192 + sp * 1024 + skc;
    const _Float16* gB1 = Htl + (size_t)(n0 + srow) * 16384 + b * 8192 + sp * 1024 + skc;
    const int lo = tid << 3;

    for (int k0 = 0; k0 < 1024; k0 += 32) {
        load16(gAh0 + k0,          sAh + lo);
        load16(gAh0 + k0 + 524288, sAh + lo + 2048);
        load16(gAl0 + k0,          sAl + lo);
        load16(gAl0 + k0 + 524288, sAl + lo + 2048);
        load16(gB0 + k0,           sBh + lo);
        load16(gB0 + k0 + 1048576, sBh + lo + 2048);
        load16(gB1 + k0,           sBl + lo);
        load16(gB1 + k0 + 1048576, sBl + lo + 2048);
        __syncthreads();

        f16x8 ah[4], al[4], bh[4], bl[4];
        #pragma unroll
        for (int i = 0; i < 4; i++) {
            int ra = (fm + i * 16 + lm) * 32 + lq * 8;
            ah[i] = *(const f16x8*)(sAh + ra);
            al[i] = *(const f16x8*)(sAl + ra);
            int rb_ = (fn + i * 16 + lm) * 32 + lq * 8;
            bh[i] = *(const f16x8*)(sBh + rb_);
            bl[i] = *(const f16x8*)(sBl + rb_);
        }
        #pragma unroll
        for (int i = 0; i < 4; i++)
            #pragma unroll
            for (int j = 0; j < 4; j++) {
                acc[i][j] = __builtin_amdgcn_mfma_f32_16x16x32_f16(ah[i], bh[j], acc[i][j], 0, 0, 0);
                acc[i][j] = __builtin_amdgcn_mfma_f32_16x16x32_f16(ah[i], bl[j], acc[i][j], 0, 0, 0);
                acc[i][j] = __builtin_amdgcn_mfma_f32_16x16x32_f16(al[i], bh[j], acc[i][j], 0, 0, 0);
            }
        __syncthreads();
    }

    float* Pz = P + (size_t)z * 262144;
    #pragma unroll
    for (int j = 0; j < 4; j++) {
        int n = n0 + fn + j * 16 + lm;
        #pragma unroll
        for (int i = 0; i < 4; i++)
            #pragma unroll
            for (int r = 0; r < 4; r++) {
                int k = m0 + fm + i * 16 + lq * 4 + r;
                Pz[(size_t)k * 1024 + n] = acc[i][j][r];
            }
    }
}

__global__ __launch_bounds__(256)
void sel_reduce(const float* __restrict__ P, float* __restrict__ SEL)
{
    int idx4 = blockIdx.x * 256 + threadIdx.x;   // 131072 total
    int e = idx4 << 2;
    int b = e >> 18;
    int rest = e & 262143;
    const float* p = P + (size_t)(b * 8) * 262144 + rest;
    float4 acc = {0.f, 0.f, 0.f, 0.f};
    #pragma unroll
    for (int s = 0; s < 8; s++) {
        float4 v = *(const float4*)(p + (size_t)s * 262144);
        acc.x += v.x; acc.y += v.y; acc.z += v.z; acc.w += v.w;
    }
    *(float4*)(SEL + e) = acc;
}

// multi-scale pooling into output [B, 256+128+64, 1024]
__global__ __launch_bounds__(256)
void pool_kernel(const float* __restrict__ SEL, float* __restrict__ out)
{
    int i4 = blockIdx.x * 256 + threadIdx.x;
    int e  = i4 << 2;
    int row = e >> 10;
    int b = row / 448;
    int r = row - b * 448;
    int c = e & 1023;
    const float* sb = SEL + (size_t)b * (256 * 1024);
    float4 o;
    if (r < 256) {
        o = *(const float4*)(sb + (size_t)r * 1024 + c);
    } else if (r < 384) {
        int r2 = (r - 256) * 2;
        float4 x0 = *(const float4*)(sb + (size_t)r2 * 1024 + c);
        float4 x1 = *(const float4*)(sb + (size_t)(r2 + 1) * 1024 + c);
        o.x = 0.5f * (x0.x + x1.x); o.y = 0.5f * (x0.y + x1.y);
        o.z = 0.5f * (x0.z + x1.z); o.w = 0.5f * (x0.w + x1.w);
    } else {
        int r4 = (r - 384) * 4;
        float4 x0 = *(const float4*)(sb + (size_t)(r4 + 0) * 1024 + c);
        float4 x1 = *(const float4*)(sb + (size_t)(r4 + 1) * 1024 + c);
        float4 x2 = *(const float4*)(sb + (size_t)(r4 + 2) * 1024 + c);
        float4 x3 = *(const float4*)(sb + (size_t)(r4 + 3) * 1024 + c);
        o.x = 0.25f * (x0.x + x1.x + x2.x + x3.x);
        o.y = 0.25f * (x0.y + x1.y + x2.y + x3.y);
        o.z = 0.25f * (x0.z + x1.z + x2.z + x3.z);
        o.w = 0.25f * (x0.w + x1.w + x2.w + x3.w);
    }
    *(float4*)(out + e) = o;
}

// ---------------------------------------------------------------------------
extern "C" void kernel_launch(void* const* d_in, const int* in_sizes, int n_in,
                              void* d_out, int out_size, void* d_ws, size_t ws_size,
                              hipStream_t stream)
{
    const float* x    = (const float*)d_in[0];
    const float* wq   = (const float*)d_in[1];
    const float* bq   = (const float*)d_in[2];
    const float* wk   = (const float*)d_in[3];
    const float* bk   = (const float*)d_in[4];
    const float* wv   = (const float*)d_in[5];
    const float* bv   = (const float*)d_in[6];
    const float* wd   = (const float*)d_in[7];
    const float* bd   = (const float*)d_in[8];
    const float* rb   = (const float*)d_in[9];
    const float* selw = (const float*)d_in[10];
    const float* selb = (const float*)d_in[11];
    float* out = (float*)d_out;

    // layout (floats), 240 MB total:
    float* Q = (float*)d_ws;                 // 8,388,608 (chunk QKV fp32)
    float* K = Q + 8388608;
    float* V = K + 8388608;
    _Float16* Ah  = (_Float16*)(V + 8388608);   // 2 x 8,388,608 f16 (x-split chunk)
    _Float16* Al  = Ah + 8388608;
    _Float16* CXh = (_Float16*)((float*)d_ws + 33554432);  // ctx split chunk
    _Float16* CXl = CXh + 8388608;
    _Float16* Hh  = (_Float16*)((float*)d_ws + 41943040);  // H split full
    _Float16* Hl  = Hh + 16777216;
    _Float16* WTh = (_Float16*)((float*)d_ws + 58720256);  // weights split-T
    _Float16* WTl = WTh + 4194304;
    // selection aliases:
    float* SC   = Q;                         // [16384][256]
    float* Pp   = K;                         // [16][256][1024] partials
    float* SEL  = K + 4194304;               // [2][256][1024]
    float* PART = SEL + 524288;
    float* CSUM = PART + 65536;
    _Float16* HTh  = (_Float16*)V;           // [1024][16384]
    _Float16* HTl  = Ah;                     // spans Ah..Al
    _Float16* WTTh = CXh;                    // [2][256][8192]
    _Float16* WTTl = CXl;

    const dim3 blk(256);
    const dim3 blk128(128);

    for (int a = 0; a < 4; a++) {
        const int mi = (a & 1);
        const size_t wo = (size_t)a * 1048576;
        const int bo = a * 1024;
        const float* rba = rb + (size_t)a * 1023 * 16;

        conv_wT<<<dim3(16, 16), blk, 0, stream>>>(wq + wo, WTh,           WTl,           1024);
        conv_wT<<<dim3(16, 16), blk, 0, stream>>>(wk + wo, WTh + 1048576, WTl + 1048576, 1024);
        conv_wT<<<dim3(16, 16), blk, 0, stream>>>(wv + wo, WTh + 2097152, WTl + 2097152, 1024);
        conv_wT<<<dim3(16, 16), blk, 0, stream>>>(wd + wo, WTh + 3145728, WTl + 3145728, 1024);

        for (int c = 0; c < 2; c++) {
            const int mo = c * 8192;
            const _Float16 *srcH, *srcL;
            int smap, soff;
            if (a == 0) {
                conv_act<<<4096, blk, 0, stream>>>(x, Ah, Al, mo);
                srcH = Ah; srcL = Al; smap = 0; soff = 0;
            } else {
                srcH = Hh; srcL = Hl; smap = mi; soff = mo;
            }
            gemm_f16s_qkv3<<<dim3(8, 64, 3), blk, 0, stream>>>(
                srcH, srcL, smap, soff, WTh, WTl, bq + bo, bk + bo, bv + bo, Q, K, V);
            if (mi == 0)
                attn_s<<<dim3(64, 16), blk128, 0, stream>>>(Q, K, V, rba, CXh, CXl);
            else
                attn_t<<<dim3(256, 4), blk128, 0, stream>>>(Q, K, V, rba, CXh, CXl);
            gemm_f16s_h<<<dim3(8, 64), blk, 0, stream>>>(
                CXh, CXl, 0, 0, WTh + 3145728, WTl + 3145728, bd + bo, Hh, Hl, mi, mo);
        }
    }

    // token selection
    conv_wT<<<dim3(4, 16), blk, 0, stream>>>(selw, WTh, WTl, 256);
    gemm_f16s_f32<<<dim3(2, 128), blk, 0, stream>>>(
        Hh, Hl, 0, 0, WTh, WTl, selb, SC, 256, 0, 0);
    colsum_part_kernel<<<256, blk, 0, stream>>>(SC, PART);
    colsum_reduce_kernel<<<2, blk, 0, stream>>>(PART, CSUM);
    trans_wts<<<dim3(256, 4), blk, 0, stream>>>(SC, CSUM, WTTh, WTTl);
    trans_f16<<<dim3(256, 16, 2), blk, 0, stream>>>(Hh, Hl, HTh, HTl);
    gemm_selm<<<dim3(8, 2, 16), blk, 0, stream>>>(WTTh, WTTl, HTh, HTl, Pp);
    sel_reduce<<<512, blk, 0, stream>>>(Pp, SEL);
    pool_kernel<<<896, blk, 0, stream>>>(SEL, out);
}

// Round 6
// 2506.788 us; speedup vs baseline: 4.8672x; 1.3848x over previous
//
#include <hip/hip_runtime.h>
#include <stdint.h>

// B=2, T=32, N=256, E=1024, H=16, D=64, L=2, K=256, MAXLEN=512
// tokens = 16384, GEMMs/attention chunked in 2 x 8192 rows.

using f16x8 = __attribute__((ext_vector_type(8))) _Float16;
using f16x4 = __attribute__((ext_vector_type(4))) _Float16;
using f32x4 = __attribute__((ext_vector_type(4))) float;

__device__ __forceinline__ int tmap_dev(int m) {
    // temporal token m = (b*N+n)*T + t  ->  flat row (b*T+t)*N + n
    int bx = m >> 5;
    int s  = m & 31;
    int b  = bx >> 8;
    int n  = bx & 255;
    return (((b << 5) + s) << 8) + n;
}

__device__ __forceinline__ void load16(const _Float16* g, _Float16* l)
{
    __builtin_amdgcn_global_load_lds(
        (const __attribute__((address_space(1))) unsigned int*)g,
        (__attribute__((address_space(3))) unsigned int*)l,
        16, 0, 0);
}

__device__ __forceinline__ void split_f16(float v, _Float16& h, _Float16& l)
{
    h = (_Float16)v;
    l = (_Float16)(v - (float)h);
}

// ---------------------------------------------------------------------------
// x fp32 -> split f16 hi/lo (a=0 only, identity map). chunk-local dst.
// ---------------------------------------------------------------------------
__global__ __launch_bounds__(256)
void conv_act(const float* __restrict__ src, _Float16* __restrict__ dh,
              _Float16* __restrict__ dl, int m_off)
{
    int idx = blockIdx.x * 256 + threadIdx.x;
    int e = idx << 3;
    int ml = e >> 10, col = e & 1023;
    const float* s = src + (size_t)(m_off + ml) * 1024 + col;
    float4 a = *(const float4*)s;
    float4 b = *(const float4*)(s + 4);
    float vv[8] = {a.x, a.y, a.z, a.w, b.x, b.y, b.z, b.w};
    f16x8 vh, vl;
    #pragma unroll
    for (int r = 0; r < 8; r++) {
        _Float16 h, l;
        split_f16(vv[r], h, l);
        vh[r] = h; vl[r] = l;
    }
    *(f16x8*)(dh + (size_t)ml * 1024 + col) = vh;
    *(f16x8*)(dl + (size_t)ml * 1024 + col) = vl;
}

// ---------------------------------------------------------------------------
// Weight fp32 [1024][ncols] -> transposed split f16 [ncols][1024].
// ---------------------------------------------------------------------------
__global__ __launch_bounds__(256)
void conv_wT(const float* __restrict__ W, _Float16* __restrict__ Th,
             _Float16* __restrict__ Tl, int ncols)
{
    __shared__ float Ls[64][65];
    const int n0 = blockIdx.x * 64, k0 = blockIdx.y * 64;
    const int t = threadIdx.x;
    const int kk = t >> 4, nn = (t & 15) << 2;
    #pragma unroll
    for (int i = 0; i < 4; i++) {
        float4 v = *(const float4*)(W + (size_t)(k0 + kk + 16 * i) * ncols + n0 + nn);
        Ls[kk + 16 * i][nn + 0] = v.x; Ls[kk + 16 * i][nn + 1] = v.y;
        Ls[kk + 16 * i][nn + 2] = v.z; Ls[kk + 16 * i][nn + 3] = v.w;
    }
    __syncthreads();
    const int nl = t >> 4, kc = (t & 15) << 2;
    #pragma unroll
    for (int i = 0; i < 4; i++) {
        int n = nl + 16 * i;
        f16x4 hh, ll;
        #pragma unroll
        for (int c = 0; c < 4; c++) {
            _Float16 h, l;
            split_f16(Ls[kc + c][n], h, l);
            hh[c] = h; ll[c] = l;
        }
        *(f16x4*)(Th + (size_t)(n0 + n) * 1024 + k0 + kc) = hh;
        *(f16x4*)(Tl + (size_t)(n0 + n) * 1024 + k0 + kc) = ll;
    }
}

// ---------------------------------------------------------------------------
// Split-f16 MFMA GEMM core, tile 128x128, BK=32, K=1024, lda/ldb=1024.
// EPI 0: fp32 C (scatter map). EPI 1: split-f16 [row][1024] (scatter map).
// EPI 3: transposed split-f16 C^T[n][8192] (V^T output; no map).
// ---------------------------------------------------------------------------
template<int EPI>
__device__ __forceinline__ void gemm_core(
    const _Float16* __restrict__ Ah, const _Float16* __restrict__ Al,
    const _Float16* __restrict__ Wh, const _Float16* __restrict__ Wl,
    const float* __restrict__ bias,
    float* __restrict__ C, _Float16* __restrict__ Ch, _Float16* __restrict__ Cl,
    int ldc, int map_in, int m_off_in, int map_out, int m_off_out,
    int n0, int m0)
{
    __shared__ uint32_t smem_u[8512];   // 34 KB: staging (32 KB) + EPI3 transpose
    _Float16* smem = (_Float16*)smem_u;
    _Float16* sAh = smem;
    _Float16* sAl = smem + 4096;
    _Float16* sBh = smem + 8192;
    _Float16* sBl = smem + 12288;

    const int tid = threadIdx.x;
    const int lane = tid & 63;
    const int wv = tid >> 6;
    const int fm = (wv >> 1) << 6;
    const int fn = (wv & 1) << 6;
    const int lm = lane & 15, lq = lane >> 4;

    f32x4 acc[4][4] = {};

    const int srow = tid >> 2;
    const int skc  = (tid & 3) << 3;
    const int gm0 = m_off_in + m0 + srow;
    const int gm1 = gm0 + 64;
    const int r0 = map_in ? tmap_dev(gm0) : gm0;
    const int r1 = map_in ? tmap_dev(gm1) : gm1;
    const _Float16* gAh0 = Ah + (size_t)r0 * 1024 + skc;
    const _Float16* gAh1 = Ah + (size_t)r1 * 1024 + skc;
    const _Float16* gAl0 = Al + (size_t)r0 * 1024 + skc;
    const _Float16* gAl1 = Al + (size_t)r1 * 1024 + skc;
    const _Float16* gB0 = Wh + (size_t)(n0 + srow) * 1024 + skc;
    const _Float16* gB1 = Wl + (size_t)(n0 + srow) * 1024 + skc;
    const int lo = tid << 3;

    for (int k0 = 0; k0 < 1024; k0 += 32) {
        load16(gAh0 + k0, sAh + lo);
        load16(gAh1 + k0, sAh + lo + 2048);
        load16(gAl0 + k0, sAl + lo);
        load16(gAl1 + k0, sAl + lo + 2048);
        load16(gB0 + k0,         sBh + lo);
        load16(gB0 + k0 + 65536, sBh + lo + 2048);
        load16(gB1 + k0,         sBl + lo);
        load16(gB1 + k0 + 65536, sBl + lo + 2048);
        __syncthreads();

        f16x8 ah[4], al[4], bh[4], bl[4];
        #pragma unroll
        for (int i = 0; i < 4; i++) {
            int ra = (fm + i * 16 + lm) * 32 + lq * 8;
            ah[i] = *(const f16x8*)(sAh + ra);
            al[i] = *(const f16x8*)(sAl + ra);
            int rb_ = (fn + i * 16 + lm) * 32 + lq * 8;
            bh[i] = *(const f16x8*)(sBh + rb_);
            bl[i] = *(const f16x8*)(sBl + rb_);
        }
        #pragma unroll
        for (int i = 0; i < 4; i++)
            #pragma unroll
            for (int j = 0; j < 4; j++) {
                acc[i][j] = __builtin_amdgcn_mfma_f32_16x16x32_f16(ah[i], bh[j], acc[i][j], 0, 0, 0);
                acc[i][j] = __builtin_amdgcn_mfma_f32_16x16x32_f16(ah[i], bl[j], acc[i][j], 0, 0, 0);
                acc[i][j] = __builtin_amdgcn_mfma_f32_16x16x32_f16(al[i], bh[j], acc[i][j], 0, 0, 0);
            }
        __syncthreads();
    }

    if (EPI == 0 || EPI == 1) {
        #pragma unroll
        for (int j = 0; j < 4; j++) {
            int n = n0 + fn + j * 16 + lm;
            float bb = bias[n];
            #pragma unroll
            for (int i = 0; i < 4; i++) {
                #pragma unroll
                for (int r = 0; r < 4; r++) {
                    int gm = m_off_out + m0 + fm + i * 16 + lq * 4 + r;
                    int row = map_out ? tmap_dev(gm) : gm;
                    float v = acc[i][j][r] + bb;
                    if (EPI == 0) {
                        C[(size_t)row * ldc + n] = v;
                    } else {
                        _Float16 h, l;
                        split_f16(v, h, l);
                        Ch[(size_t)row * 1024 + n] = h;
                        Cl[(size_t)row * 1024 + n] = l;
                    }
                }
            }
        }
    } else {
        // EPI 3: write C^T as split f16, [n_global][8192 rows], via LDS transpose.
        const int fmh = fm >> 6;
        #pragma unroll
        for (int mh = 0; mh < 2; mh++) {
            __syncthreads();
            if (fmh == mh) {
                #pragma unroll
                for (int j = 0; j < 4; j++) {
                    int n = fn + j * 16 + lm;
                    float bb = bias[n0 + n];
                    #pragma unroll
                    for (int i = 0; i < 4; i++) {
                        #pragma unroll
                        for (int r = 0; r < 4; r++) {
                            float v = acc[i][j][r] + bb;
                            _Float16 h, l;
                            split_f16(v, h, l);
                            uint32_t ph = (uint32_t)__builtin_bit_cast(unsigned short, h);
                            uint32_t pl = (uint32_t)__builtin_bit_cast(unsigned short, l);
                            smem_u[(i * 16 + lq * 4 + r) * 133 + n] = ph | (pl << 16);
                        }
                    }
                }
            }
            __syncthreads();
            #pragma unroll
            for (int g = 0; g < 8; g++) {
                int u = tid + g * 256;
                int nn = u >> 4;
                int mg = (u & 15) << 2;
                uint32_t p0 = smem_u[(mg + 0) * 133 + nn];
                uint32_t p1 = smem_u[(mg + 1) * 133 + nn];
                uint32_t p2 = smem_u[(mg + 2) * 133 + nn];
                uint32_t p3 = smem_u[(mg + 3) * 133 + nn];
                f16x4 hh, ll;
                hh[0] = __builtin_bit_cast(_Float16, (unsigned short)(p0 & 0xffff));
                hh[1] = __builtin_bit_cast(_Float16, (unsigned short)(p1 & 0xffff));
                hh[2] = __builtin_bit_cast(_Float16, (unsigned short)(p2 & 0xffff));
                hh[3] = __builtin_bit_cast(_Float16, (unsigned short)(p3 & 0xffff));
                ll[0] = __builtin_bit_cast(_Float16, (unsigned short)(p0 >> 16));
                ll[1] = __builtin_bit_cast(_Float16, (unsigned short)(p1 >> 16));
                ll[2] = __builtin_bit_cast(_Float16, (unsigned short)(p2 >> 16));
                ll[3] = __builtin_bit_cast(_Float16, (unsigned short)(p3 >> 16));
                size_t off = (size_t)(n0 + nn) * 8192 + (m0 + mh * 64 + mg);
                *(f16x4*)(Ch + off) = hh;
                *(f16x4*)(Cl + off) = ll;
            }
        }
    }
}

__global__ __launch_bounds__(256, 2)
void gemm_f16s_f32(const _Float16* __restrict__ Ah, const _Float16* __restrict__ Al,
                   int map_in, int m_off_in,
                   const _Float16* __restrict__ Wh, const _Float16* __restrict__ Wl,
                   const float* __restrict__ bias, float* __restrict__ C, int ldc,
                   int map_out, int m_off_out)
{
    gemm_core<0>(Ah, Al, Wh, Wl, bias, C, nullptr, nullptr, ldc,
                 map_in, m_off_in, map_out, m_off_out,
                 blockIdx.x * 128, blockIdx.y * 128);
}

__global__ __launch_bounds__(256, 2)
void gemm_f16s_h(const _Float16* __restrict__ Ah, const _Float16* __restrict__ Al,
                 int map_in, int m_off_in,
                 const _Float16* __restrict__ Wh, const _Float16* __restrict__ Wl,
                 const float* __restrict__ bias,
                 _Float16* __restrict__ Ch, _Float16* __restrict__ Cl,
                 int map_out, int m_off_out)
{
    gemm_core<1>(Ah, Al, Wh, Wl, bias, nullptr, Ch, Cl, 1024,
                 map_in, m_off_in, map_out, m_off_out,
                 blockIdx.x * 128, blockIdx.y * 128);
}

// QKV projection: z=0 -> Qh/Ql, z=1 -> Kh/Kl (split rows), z=2 -> VT (transposed)
__global__ __launch_bounds__(256, 2)
void gemm_qkvsplit(const _Float16* __restrict__ Ah, const _Float16* __restrict__ Al,
                   int map_in, int m_off_in,
                   const _Float16* __restrict__ WTh, const _Float16* __restrict__ WTl,
                   const float* __restrict__ bq, const float* __restrict__ bk,
                   const float* __restrict__ bv,
                   _Float16* __restrict__ Qh, _Float16* __restrict__ Ql,
                   _Float16* __restrict__ Kh, _Float16* __restrict__ Kl,
                   _Float16* __restrict__ VTh, _Float16* __restrict__ VTl)
{
    const int z = blockIdx.z;
    const _Float16* wh = WTh + (size_t)z * 1048576;
    const _Float16* wl = WTl + (size_t)z * 1048576;
    if (z == 0)
        gemm_core<1>(Ah, Al, wh, wl, bq, nullptr, Qh, Ql, 1024,
                     map_in, m_off_in, 0, 0, blockIdx.x * 128, blockIdx.y * 128);
    else if (z == 1)
        gemm_core<1>(Ah, Al, wh, wl, bk, nullptr, Kh, Kl, 1024,
                     map_in, m_off_in, 0, 0, blockIdx.x * 128, blockIdx.y * 128);
    else
        gemm_core<3>(Ah, Al, wh, wl, bv, nullptr, VTh, VTl, 0,
                     map_in, m_off_in, 0, 0, blockIdx.x * 128, blockIdx.y * 128);
}

// ---------------------------------------------------------------------------
// Spatial attention via MFMA, S=256. One workgroup per (frame, head).
// 4 waves; wave w owns query rows [w*64, w*64+64). j processed in 8 chunks
// of 32. S^T = K@Q^T (split-f16 MFMA), exp (no max sub: |sc| << 88),
// P packed per-wave to LDS in B-operand layout, ctx^T = V^T@P^T (MFMA).
// grid: (32, 16) per chunk.
// ---------------------------------------------------------------------------
__global__ __launch_bounds__(256, 2)
void attn_s_m(const _Float16* __restrict__ Qh, const _Float16* __restrict__ Ql,
              const _Float16* __restrict__ Kh, const _Float16* __restrict__ Kl,
              const _Float16* __restrict__ VTh, const _Float16* __restrict__ VTl,
              const float* __restrict__ RB,
              _Float16* __restrict__ Ch, _Float16* __restrict__ Cl)
{
    __shared__ _Float16 sKh[2048], sKl[2048];      // [32 j][64 d]
    __shared__ _Float16 sVh[2560], sVl[2560];      // [64 d][40] (32 j + pad)
    __shared__ _Float16 sPh[4][2560], sPl[4][2560];// per-wave [64 s][40]
    __shared__ float Bt[512];

    const int tid = threadIdx.x;
    const int lane = tid & 63;
    const int w = tid >> 6;
    const int lm = lane & 15, lq = lane >> 4;
    const int frame = blockIdx.x;
    const int h = blockIdx.y;
    const int rowbase = frame * 256;

    #pragma unroll
    for (int l = 0; l < 2; l++) {
        int idx = tid + l * 256;
        if (idx < 511) Bt[idx] = RB[(size_t)(256 + idx) * 16 + h];
    }

    // Q B-frags in registers
    f16x8 qbh[4][2], qbl[4][2];
    #pragma unroll
    for (int st = 0; st < 4; st++)
        #pragma unroll
        for (int kk = 0; kk < 2; kk++) {
            size_t qo = (size_t)(rowbase + w * 64 + st * 16 + lm) * 1024
                        + h * 64 + kk * 32 + lq * 8;
            qbh[st][kk] = *(const f16x8*)(Qh + qo);
            qbl[st][kk] = *(const f16x8*)(Ql + qo);
        }

    f32x4 cacc[4][4] = {};
    float lsum[4] = {0.f, 0.f, 0.f, 0.f};
    _Float16* Ph = sPh[w];
    _Float16* Pl = sPl[w];

    const int skrow = tid >> 3, skd = (tid & 7) << 3;
    const int svrow = tid >> 2, svj = (tid & 3) << 3;

    for (int jc = 0; jc < 8; jc++) {
        __syncthreads();
        {
            size_t ko = (size_t)(rowbase + jc * 32 + skrow) * 1024 + h * 64 + skd;
            *(f16x8*)(sKh + skrow * 64 + skd) = *(const f16x8*)(Kh + ko);
            *(f16x8*)(sKl + skrow * 64 + skd) = *(const f16x8*)(Kl + ko);
            size_t vo = (size_t)(h * 64 + svrow) * 8192 + rowbase + jc * 32 + svj;
            *(f16x8*)(sVh + svrow * 40 + svj) = *(const f16x8*)(VTh + vo);
            *(f16x8*)(sVl + svrow * 40 + svj) = *(const f16x8*)(VTl + vo);
        }
        __syncthreads();

        // S^T = K @ Q^T
        f32x4 sacc[2][4] = {};
        #pragma unroll
        for (int jt = 0; jt < 2; jt++) {
            f16x8 kah[2], kal[2];
            #pragma unroll
            for (int kk = 0; kk < 2; kk++) {
                int ra = (jt * 16 + lm) * 64 + kk * 32 + lq * 8;
                kah[kk] = *(const f16x8*)(sKh + ra);
                kal[kk] = *(const f16x8*)(sKl + ra);
            }
            #pragma unroll
            for (int st = 0; st < 4; st++)
                #pragma unroll
                for (int kk = 0; kk < 2; kk++) {
                    sacc[jt][st] = __builtin_amdgcn_mfma_f32_16x16x32_f16(kah[kk], qbh[st][kk], sacc[jt][st], 0, 0, 0);
                    sacc[jt][st] = __builtin_amdgcn_mfma_f32_16x16x32_f16(kah[kk], qbl[st][kk], sacc[jt][st], 0, 0, 0);
                    sacc[jt][st] = __builtin_amdgcn_mfma_f32_16x16x32_f16(kal[kk], qbh[st][kk], sacc[jt][st], 0, 0, 0);
                }
        }

        // bias + exp + pack P into per-wave LDS ([s][40], j-consecutive)
        #pragma unroll
        for (int jt = 0; jt < 2; jt++)
            #pragma unroll
            for (int st = 0; st < 4; st++) {
                f16x4 p4h, p4l;
                #pragma unroll
                for (int r = 0; r < 4; r++) {
                    int j = jc * 32 + jt * 16 + lq * 4 + r;
                    int s = w * 64 + st * 16 + lm;
                    float p = __expf(sacc[jt][st][r] * 0.125f + Bt[j - s + 255]);
                    lsum[st] += p;
                    _Float16 hp, lp;
                    split_f16(p, hp, lp);
                    p4h[r] = hp; p4l[r] = lp;
                }
                int pa = (st * 16 + lm) * 40 + jt * 16 + lq * 4;
                *(f16x4*)(Ph + pa) = p4h;
                *(f16x4*)(Pl + pa) = p4l;
            }

        // ctx^T += V^T @ P^T   (per-wave P; compiler orders LDS RAW)
        #pragma unroll
        for (int st = 0; st < 4; st++) {
            int pb = (st * 16 + lm) * 40 + lq * 8;
            f16x8 pbh = *(const f16x8*)(Ph + pb);
            f16x8 pbl = *(const f16x8*)(Pl + pb);
            #pragma unroll
            for (int dt = 0; dt < 4; dt++) {
                int va = (dt * 16 + lm) * 40 + lq * 8;
                f16x8 vah = *(const f16x8*)(sVh + va);
                f16x8 val = *(const f16x8*)(sVl + va);
                cacc[dt][st] = __builtin_amdgcn_mfma_f32_16x16x32_f16(vah, pbh, cacc[dt][st], 0, 0, 0);
                cacc[dt][st] = __builtin_amdgcn_mfma_f32_16x16x32_f16(vah, pbl, cacc[dt][st], 0, 0, 0);
                cacc[dt][st] = __builtin_amdgcn_mfma_f32_16x16x32_f16(val, pbh, cacc[dt][st], 0, 0, 0);
            }
        }
    }

    float inv[4];
    #pragma unroll
    for (int st = 0; st < 4; st++) {
        float t = lsum[st];
        t += __shfl_xor(t, 16);
        t += __shfl_xor(t, 32);
        inv[st] = 1.0f / t;
    }

    #pragma unroll
    for (int st = 0; st < 4; st++)
        #pragma unroll
        for (int dt = 0; dt < 4; dt++) {
            f16x4 oh, ol;
            #pragma unroll
            for (int r = 0; r < 4; r++) {
                _Float16 hp, lp;
                split_f16(cacc[dt][st][r] * inv[st], hp, lp);
                oh[r] = hp; ol[r] = lp;
            }
            size_t oo = (size_t)(rowbase + w * 64 + st * 16 + lm) * 1024
                        + h * 64 + dt * 16 + lq * 4;
            *(f16x4*)(Ch + oo) = oh;
            *(f16x4*)(Cl + oo) = ol;
        }
}

// ---------------------------------------------------------------------------
// Temporal attention via MFMA, S=32. One wave per (bx, head); 4 waves/wg
// share a head. All operands register/global-direct; P via per-wave LDS.
// grid: (64, 16) per chunk.
// ---------------------------------------------------------------------------
__global__ __launch_bounds__(256, 2)
void attn_t_m(const _Float16* __restrict__ Qh, const _Float16* __restrict__ Ql,
              const _Float16* __restrict__ Kh, const _Float16* __restrict__ Kl,
              const _Float16* __restrict__ VTh, const _Float16* __restrict__ VTl,
              const float* __restrict__ RB,
              _Float16* __restrict__ Ch, _Float16* __restrict__ Cl)
{
    __shared__ _Float16 sPh[4][1280], sPl[4][1280];  // per-wave [32 s][40]
    __shared__ float Bt[64];

    const int tid = threadIdx.x;
    const int lane = tid & 63;
    const int w = tid >> 6;
    const int lm = lane & 15, lq = lane >> 4;
    const int h = blockIdx.y;
    const int bx = blockIdx.x * 4 + w;
    const int rowbase = bx * 32;

    if (tid < 63) Bt[tid] = RB[(size_t)(480 + tid) * 16 + h];
    __syncthreads();

    // Q B-frags
    f16x8 qbh[2][2], qbl[2][2];
    #pragma unroll
    for (int st = 0; st < 2; st++)
        #pragma unroll
        for (int kk = 0; kk < 2; kk++) {
            size_t qo = (size_t)(rowbase + st * 16 + lm) * 1024 + h * 64 + kk * 32 + lq * 8;
            qbh[st][kk] = *(const f16x8*)(Qh + qo);
            qbl[st][kk] = *(const f16x8*)(Ql + qo);
        }

    // S^T = K @ Q^T
    f32x4 sacc[2][2] = {};
    #pragma unroll
    for (int jt = 0; jt < 2; jt++) {
        f16x8 kah[2], kal[2];
        #pragma unroll
        for (int kk = 0; kk < 2; kk++) {
            size_t ko = (size_t)(rowbase + jt * 16 + lm) * 1024 + h * 64 + kk * 32 + lq * 8;
            kah[kk] = *(const f16x8*)(Kh + ko);
            kal[kk] = *(const f16x8*)(Kl + ko);
        }
        #pragma unroll
        for (int st = 0; st < 2; st++)
            #pragma unroll
            for (int kk = 0; kk < 2; kk++) {
                sacc[jt][st] = __builtin_amdgcn_mfma_f32_16x16x32_f16(kah[kk], qbh[st][kk], sacc[jt][st], 0, 0, 0);
                sacc[jt][st] = __builtin_amdgcn_mfma_f32_16x16x32_f16(kah[kk], qbl[st][kk], sacc[jt][st], 0, 0, 0);
                sacc[jt][st] = __builtin_amdgcn_mfma_f32_16x16x32_f16(kal[kk], qbh[st][kk], sacc[jt][st], 0, 0, 0);
            }
    }

    // bias + exp + pack
    float lsum[2] = {0.f, 0.f};
    _Float16* Ph = sPh[w];
    _Float16* Pl = sPl[w];
    #pragma unroll
    for (int jt = 0; jt < 2; jt++)
        #pragma unroll
        for (int st = 0; st < 2; st++) {
            f16x4 p4h, p4l;
            #pragma unroll
            for (int r = 0; r < 4; r++) {
                int j = jt * 16 + lq * 4 + r;
                int s = st * 16 + lm;
                float p = __expf(sacc[jt][st][r] * 0.125f + Bt[j - s + 31]);
                lsum[st] += p;
                _Float16 hp, lp;
                split_f16(p, hp, lp);
                p4h[r] = hp; p4l[r] = lp;
            }
            int pa = (st * 16 + lm) * 40 + jt * 16 + lq * 4;
            *(f16x4*)(Ph + pa) = p4h;
            *(f16x4*)(Pl + pa) = p4l;
        }

    // ctx^T = V^T @ P^T
    f16x8 vah[4], val[4];
    #pragma unroll
    for (int dt = 0; dt < 4; dt++) {
        size_t vo = (size_t)(h * 64 + dt * 16 + lm) * 8192 + rowbase + lq * 8;
        vah[dt] = *(const f16x8*)(VTh + vo);
        val[dt] = *(const f16x8*)(VTl + vo);
    }
    f32x4 cacc[4][2] = {};
    #pragma unroll
    for (int st = 0; st < 2; st++) {
        int pb = (st * 16 + lm) * 40 + lq * 8;
        f16x8 pbh = *(const f16x8*)(Ph + pb);
        f16x8 pbl = *(const f16x8*)(Pl + pb);
        #pragma unroll
        for (int dt = 0; dt < 4; dt++) {
            cacc[dt][st] = __builtin_amdgcn_mfma_f32_16x16x32_f16(vah[dt], pbh, cacc[dt][st], 0, 0, 0);
            cacc[dt][st] = __builtin_amdgcn_mfma_f32_16x16x32_f16(vah[dt], pbl, cacc[dt][st], 0, 0, 0);
            cacc[dt][st] = __builtin_amdgcn_mfma_f32_16x16x32_f16(val[dt], pbh, cacc[dt][st], 0, 0, 0);
        }
    }

    float inv[2];
    #pragma unroll
    for (int st = 0; st < 2; st++) {
        float t = lsum[st];
        t += __shfl_xor(t, 16);
        t += __shfl_xor(t, 32);
        inv[st] = 1.0f / t;
    }

    #pragma unroll
    for (int st = 0; st < 2; st++)
        #pragma unroll
        for (int dt = 0; dt < 4; dt++) {
            f16x4 oh, ol;
            #pragma unroll
            for (int r = 0; r < 4; r++) {
                _Float16 hp, lp;
                split_f16(cacc[dt][st][r] * inv[st], hp, lp);
                oh[r] = hp; ol[r] = lp;
            }
            size_t oo = (size_t)(rowbase + st * 16 + lm) * 1024 + h * 64 + dt * 16 + lq * 4;
            *(f16x4*)(Ch + oo) = oh;
            *(f16x4*)(Cl + oo) = ol;
        }
}

// ---------------------------------------------------------------------------
// Token selection (round-5 kernels, unchanged)
// ---------------------------------------------------------------------------
__global__ __launch_bounds__(256)
void colsum_part_kernel(const float* __restrict__ SC, float* __restrict__ P)
{
    int bid = blockIdx.x;
    int b = bid >> 7, chunk = bid & 127;
    int base = b * 8192 + chunk * 64;
    int k = threadIdx.x;
    float sum = 0.0f;
    for (int r = 0; r < 64; r++)
        sum += __expf(SC[(size_t)(base + r) * 256 + k]);
    P[(size_t)bid * 256 + k] = sum;
}

__global__ __launch_bounds__(256)
void colsum_reduce_kernel(const float* __restrict__ P, float* __restrict__ CS)
{
    int b = blockIdx.x;
    int k = threadIdx.x;
    float s = 0.0f;
    for (int c = 0; c < 128; c++)
        s += P[(size_t)(b * 128 + c) * 256 + k];
    CS[b * 256 + k] = s;
}

__global__ __launch_bounds__(256)
void trans_wts(const float* __restrict__ SC, const float* __restrict__ CS,
               _Float16* __restrict__ Th, _Float16* __restrict__ Tl)
{
    __shared__ float L[64][65];
    const int mt = blockIdx.x * 64;
    const int kt = blockIdx.y * 64;
    const int b  = mt >> 13;
    const int ml = mt & 8191;
    const int tid = threadIdx.x;
    #pragma unroll
    for (int l = 0; l < 4; l++) {
        int idx = tid + 256 * l;
        int r = idx >> 4, c4 = (idx & 15) << 2;
        float4 v = *(const float4*)(SC + (size_t)(mt + r) * 256 + kt + c4);
        L[r][c4 + 0] = __expf(v.x); L[r][c4 + 1] = __expf(v.y);
        L[r][c4 + 2] = __expf(v.z); L[r][c4 + 3] = __expf(v.w);
    }
    __syncthreads();
    #pragma unroll
    for (int l = 0; l < 4; l++) {
        int idx = tid + 256 * l;
        int rk = idx >> 4, c4 = (idx & 15) << 2;
        float inv = 1.0f / CS[b * 256 + kt + rk];
        f16x4 hh, ll;
        #pragma unroll
        for (int u = 0; u < 4; u++) {
            _Float16 h, l2;
            split_f16(L[c4 + u][rk] * inv, h, l2);
            hh[u] = h; ll[u] = l2;
        }
        size_t o = ((size_t)b * 256 + kt + rk) * 8192 + ml + c4;
        *(f16x4*)(Th + o) = hh;
        *(f16x4*)(Tl + o) = ll;
    }
}

__global__ __launch_bounds__(256)
void trans_f16(const _Float16* __restrict__ Sh, const _Float16* __restrict__ Sl,
               _Float16* __restrict__ Th, _Float16* __restrict__ Tl)
{
    __shared__ _Float16 L[64][72];
    const int mt = blockIdx.x * 64, et = blockIdx.y * 64;
    const _Float16* S = blockIdx.z ? Sl : Sh;
    _Float16* T = blockIdx.z ? Tl : Th;
    const int tid = threadIdx.x;
    #pragma unroll
    for (int l = 0; l < 2; l++) {
        int v = tid * 2 + l;
        int r = v >> 3, c8 = (v & 7) << 3;
        *(f16x8*)&L[r][c8] = *(const f16x8*)(S + (size_t)(mt + r) * 1024 + et + c8);
    }
    __syncthreads();
    #pragma unroll
    for (int l = 0; l < 2; l++) {
        int v = tid * 2 + l;
        int r = v >> 3, c8 = (v & 7) << 3;
        f16x8 o;
        #pragma unroll
        for (int u = 0; u < 8; u++) o[u] = L[c8 + u][r];
        *(f16x8*)(T + (size_t)(et + r) * 16384 + mt + c8) = o;
    }
}

__global__ __launch_bounds__(256, 2)
void gemm_selm(const _Float16* __restrict__ Wth, const _Float16* __restrict__ Wtl,
               const _Float16* __restrict__ Hth, const _Float16* __restrict__ Htl,
               float* __restrict__ P)
{
    __shared__ _Float16 sAh[4096], sAl[4096], sBh[4096], sBl[4096];
    const int tid = threadIdx.x;
    const int lane = tid & 63;
    const int wv = tid >> 6;
    const int fm = (wv >> 1) << 6;
    const int fn = (wv & 1) << 6;
    const int lm = lane & 15, lq = lane >> 4;
    const int n0 = blockIdx.x * 128;
    const int m0 = blockIdx.y * 128;
    const int z  = blockIdx.z;
    const int b = z >> 3, sp = z & 7;

    f32x4 acc[4][4] = {};

    const int srow = tid >> 2;
    const int skc  = (tid & 3) << 3;
    const _Float16* gAh0 = Wth + ((size_t)b * 256 + m0 + srow) * 8192 + sp * 1024 + skc;
    const _Float16* gAl0 = Wtl + ((size_t)b * 256 + m0 + srow) * 8192 + sp * 1024 + skc;
    const _Float16* gB0 = Hth + (size_t)(n0 + srow) * 16384 + b * 8192 + sp * 1024 + skc;
    const _Float16* gB1 = Htl + (size_t)(n0 + srow) * 16384 + b * 8192 + sp * 1024 + skc;
    const int lo = tid << 3;

    for (int k0 = 0; k0 < 1024; k0 += 32) {
        load16(gAh0 + k0,          sAh + lo);
        load16(gAh0 + k0 + 524288, sAh + lo + 2048);
        load16(gAl0 + k0,          sAl + lo);
        load16(gAl0 + k0 + 524288, sAl + lo + 2048);
        load16(gB0 + k0,           sBh + lo);
        load16(gB0 + k0 + 1048576, sBh + lo + 2048);
        load16(gB1 + k0,           sBl + lo);
        load16(gB1 + k0 + 1048576, sBl + lo + 2048);
        __syncthreads();

        f16x8 ah[4], al[4], bh[4], bl[4];
        #pragma unroll
        for (int i = 0; i < 4; i++) {
            int ra = (fm + i * 16 + lm) * 32 + lq * 8;
            ah[i] = *(const f16x8*)(sAh + ra);
            al[i] = *(const f16x8*)(sAl + ra);
            int rb_ = (fn + i * 16 + lm) * 32 + lq * 8;
            bh[i] = *(const f16x8*)(sBh + rb_);
            bl[i] = *(const f16x8*)(sBl + rb_);
        }
        #pragma unroll
        for (int i = 0; i < 4; i++)
            #pragma unroll
            for (int j = 0; j < 4; j++) {
                acc[i][j] = __builtin_amdgcn_mfma_f32_16x16x32_f16(ah[i], bh[j], acc[i][j], 0, 0, 0);
                acc[i][j] = __builtin_amdgcn_mfma_f32_16x16x32_f16(ah[i], bl[j], acc[i][j], 0, 0, 0);
                acc[i][j] = __builtin_amdgcn_mfma_f32_16x16x32_f16(al[i], bh[j], acc[i][j], 0, 0, 0);
            }
        __syncthreads();
    }

    float* Pz = P + (size_t)z * 262144;
    #pragma unroll
    for (int j = 0; j < 4; j++) {
        int n = n0 + fn + j * 16 + lm;
        #pragma unroll
        for (int i = 0; i < 4; i++)
            #pragma unroll
            for (int r = 0; r < 4; r++) {
                int k = m0 + fm + i * 16 + lq * 4 + r;
                Pz[(size_t)k * 1024 + n] = acc[i][j][r];
            }
    }
}

__global__ __launch_bounds__(256)
void sel_reduce(const float* __restrict__ P, float* __restrict__ SEL)
{
    int idx4 = blockIdx.x * 256 + threadIdx.x;
    int e = idx4 << 2;
    int b = e >> 18;
    int rest = e & 262143;
    const float* p = P + (size_t)(b * 8) * 262144 + rest;
    float4 acc = {0.f, 0.f, 0.f, 0.f};
    #pragma unroll
    for (int s = 0; s < 8; s++) {
        float4 v = *(const float4*)(p + (size_t)s * 262144);
        acc.x += v.x; acc.y += v.y; acc.z += v.z; acc.w += v.w;
    }
    *(float4*)(SEL + e) = acc;
}

__global__ __launch_bounds__(256)
void pool_kernel(const float* __restrict__ SEL, float* __restrict__ out)
{
    int i4 = blockIdx.x * 256 + threadIdx.x;
    int e  = i4 << 2;
    int row = e >> 10;
    int b = row / 448;
    int r = row - b * 448;
    int c = e & 1023;
    const float* sb = SEL + (size_t)b * (256 * 1024);
    float4 o;
    if (r < 256) {
        o = *(const float4*)(sb + (size_t)r * 1024 + c);
    } else if (r < 384) {
        int r2 = (r - 256) * 2;
        float4 x0 = *(const float4*)(sb + (size_t)r2 * 1024 + c);
        float4 x1 = *(const float4*)(sb + (size_t)(r2 + 1) * 1024 + c);
        o.x = 0.5f * (x0.x + x1.x); o.y = 0.5f * (x0.y + x1.y);
        o.z = 0.5f * (x0.z + x1.z); o.w = 0.5f * (x0.w + x1.w);
    } else {
        int r4 = (r - 384) * 4;
        float4 x0 = *(const float4*)(sb + (size_t)(r4 + 0) * 1024 + c);
        float4 x1 = *(const float4*)(sb + (size_t)(r4 + 1) * 1024 + c);
        float4 x2 = *(const float4*)(sb + (size_t)(r4 + 2) * 1024 + c);
        float4 x3 = *(const float4*)(sb + (size_t)(r4 + 3) * 1024 + c);
        o.x = 0.25f * (x0.x + x1.x + x2.x + x3.x);
        o.y = 0.25f * (x0.y + x1.y + x2.y + x3.y);
        o.z = 0.25f * (x0.z + x1.z + x2.z + x3.z);
        o.w = 0.25f * (x0.w + x1.w + x2.w + x3.w);
    }
    *(float4*)(out + e) = o;
}

// ---------------------------------------------------------------------------
extern "C" void kernel_launch(void* const* d_in, const int* in_sizes, int n_in,
                              void* d_out, int out_size, void* d_ws, size_t ws_size,
                              hipStream_t stream)
{
    const float* x    = (const float*)d_in[0];
    const float* wq   = (const float*)d_in[1];
    const float* bq   = (const float*)d_in[2];
    const float* wk   = (const float*)d_in[3];
    const float* bk   = (const float*)d_in[4];
    const float* wv   = (const float*)d_in[5];
    const float* bv   = (const float*)d_in[6];
    const float* wd   = (const float*)d_in[7];
    const float* bd   = (const float*)d_in[8];
    const float* rb   = (const float*)d_in[9];
    const float* selw = (const float*)d_in[10];
    const float* selb = (const float*)d_in[11];
    float* out = (float*)d_out;

    // workspace layout, 240 MiB (ws >= 256 MiB verified round 3):
    float* base = (float*)d_ws;
    _Float16* Hh  = (_Float16*)base;                   // 16,777,216 f16
    _Float16* Hl  = Hh + 16777216;
    _Float16* Qh  = (_Float16*)(base + 16777216);      // chunk 8192x1024 each
    _Float16* Ql  = Qh + 8388608;
    _Float16* Kh  = Ql + 8388608;
    _Float16* Kl  = Kh + 8388608;
    _Float16* VTh = (_Float16*)(base + 33554432);      // [1024][8192]
    _Float16* VTl = VTh + 8388608;
    _Float16* CXh = (_Float16*)(base + 41943040);
    _Float16* CXl = CXh + 8388608;
    _Float16* WTh = (_Float16*)(base + 50331648);      // 4x[1024][1024]
    _Float16* WTl = WTh + 4194304;
    _Float16* Ah  = (_Float16*)(base + 54525952);      // x split (a=0)
    _Float16* Al  = Ah + 8388608;
    // selection aliases (after attention stages complete):
    float* SC   = (float*)Qh;                          // [16384][256]
    float* Pp   = (float*)Kh;                          // [16][256][1024]
    float* SEL  = (float*)Kl;
    float* PART = SEL + 524288;
    float* CSUM = PART + 65536;
    _Float16* WTTh = CXh;                              // [2][256][8192]
    _Float16* WTTl = CXl;
    _Float16* HTh  = Ah;                               // [1024][16384]
    _Float16* HTl  = VTh;

    const dim3 blk(256);

    for (int a = 0; a < 4; a++) {
        const int mi = (a & 1);
        const size_t wo = (size_t)a * 1048576;
        const int bo = a * 1024;
        const float* rba = rb + (size_t)a * 1023 * 16;

        conv_wT<<<dim3(16, 16), blk, 0, stream>>>(wq + wo, WTh,           WTl,           1024);
        conv_wT<<<dim3(16, 16), blk, 0, stream>>>(wk + wo, WTh + 1048576, WTl + 1048576, 1024);
        conv_wT<<<dim3(16, 16), blk, 0, stream>>>(wv + wo, WTh + 2097152, WTl + 2097152, 1024);
        conv_wT<<<dim3(16, 16), blk, 0, stream>>>(wd + wo, WTh + 3145728, WTl + 3145728, 1024);

        for (int c = 0; c < 2; c++) {
            const int mo = c * 8192;
            const _Float16 *sH, *sL;
            int sm, so;
            if (a == 0) {
                conv_act<<<4096, blk, 0, stream>>>(x, Ah, Al, mo);
                sH = Ah; sL = Al; sm = 0; so = 0;
            } else {
                sH = Hh; sL = Hl; sm = mi; so = mo;
            }
            gemm_qkvsplit<<<dim3(8, 64, 3), blk, 0, stream>>>(
                sH, sL, sm, so, WTh, WTl, bq + bo, bk + bo, bv + bo,
                Qh, Ql, Kh, Kl, VTh, VTl);
            if (mi == 0)
                attn_s_m<<<dim3(32, 16), blk, 0, stream>>>(Qh, Ql, Kh, Kl, VTh, VTl, rba, CXh, CXl);
            else
                attn_t_m<<<dim3(64, 16), blk, 0, stream>>>(Qh, Ql, Kh, Kl, VTh, VTl, rba, CXh, CXl);
            gemm_f16s_h<<<dim3(8, 64), blk, 0, stream>>>(
                CXh, CXl, 0, 0, WTh + 3145728, WTl + 3145728, bd + bo, Hh, Hl, mi, mo);
        }
    }

    // token selection
    conv_wT<<<dim3(4, 16), blk, 0, stream>>>(selw, WTh, WTl, 256);
    gemm_f16s_f32<<<dim3(2, 128), blk, 0, stream>>>(
        Hh, Hl, 0, 0, WTh, WTl, selb, SC, 256, 0, 0);
    colsum_part_kernel<<<256, blk, 0, stream>>>(SC, PART);
    colsum_reduce_kernel<<<2, blk, 0, stream>>>(PART, CSUM);
    trans_wts<<<dim3(256, 4), blk, 0, stream>>>(SC, CSUM, WTTh, WTTl);
    trans_f16<<<dim3(256, 16, 2), blk, 0, stream>>>(Hh, Hl, HTh, HTl);
    gemm_selm<<<dim3(8, 2, 16), blk, 0, stream>>>(WTTh, WTTl, HTh, HTl, Pp);
    sel_reduce<<<512, blk, 0, stream>>>(Pp, SEL);
    pool_kernel<<<896, blk, 0, stream>>>(SEL, out);
}